// Round 10
// baseline (2461.542 us; speedup 1.0000x reference)
//
#include <hip/hip_runtime.h>
#include <hip/hip_bf16.h>
#include <math.h>

static constexpr int BATCH = 8;
static constexpr int LL1 = 2048;
static constexpr int LL2 = 1024;
static constexpr int DMODEL = 512;
static constexpr int NHEADS = 8;
static constexpr int DKH = 64;
static constexpr int TPRED = 100;

typedef unsigned short u16;
typedef unsigned int u32;
typedef unsigned long long u64;
typedef __attribute__((ext_vector_type(8))) _Float16 half8;
typedef __attribute__((ext_vector_type(4))) float f32x4;

__device__ __forceinline__ float sigm(float x) { return 1.0f / (1.0f + expf(-x)); }

// fp16 helpers (RNE)
__device__ __forceinline__ u16 f2h(float f) {
  _Float16 h = (_Float16)f;
  return __builtin_bit_cast(u16, h);
}

#define GLD16(gsrc, ldst) __builtin_amdgcn_global_load_lds( \
    (const __attribute__((address_space(1))) u32*)(gsrc),   \
    (__attribute__((address_space(3))) u32*)(ldst), 16, 0, 0)

// ---------------- embedding + posenc, writes fp32 + fp16 -------------------
__global__ void k_embed(const float* __restrict__ x, const float* __restrict__ ew,
                        const float* __restrict__ eb, float* __restrict__ out,
                        u16* __restrict__ oh) {
  int r0 = blockIdx.x * 8;          // 2048 blocks
  int tid = threadIdx.x;            // 256
  __shared__ float xr[8][64];
  for (int i = tid; i < 512; i += 256)
    xr[i >> 6][i & 63] = x[(size_t)r0 * 64 + i];
  __syncthreads();
  const float fac = -9.210340371976184f / 512.0f;
  int l0 = r0 & (LL1 - 1);
  for (int c = tid; c < DMODEL; c += 256) {
    float acc[8];
#pragma unroll
    for (int r = 0; r < 8; r++) acc[r] = eb[c];
    for (int i = 0; i < 64; i++) {
      float w = ew[i * DMODEL + c];
#pragma unroll
      for (int r = 0; r < 8; r++) acc[r] = fmaf(xr[r][i], w, acc[r]);
    }
    float divv = expf((float)(2 * (c >> 1)) * fac);
#pragma unroll
    for (int r = 0; r < 8; r++) {
      float ang = (float)(l0 + r) * divv;
      float v = acc[r] + ((c & 1) ? cosf(ang) : sinf(ang));
      size_t o = (size_t)(r0 + r) * DMODEL + c;
      out[o] = v;
      oh[o] = f2h(v);
    }
  }
}

// ---------------- MFMA GEMM, fp16 act x fp16-split weights -----------------
// C = A@(Wh + Wl/1024) + bias. 2 MFMA/product via separate accumulators.
// MULTI: N=1536 fused QKV routed per 512-col block. OSINGLE: fp16 output.
template <int EPI, int CONV, int OSINGLE, int MULTI>
__global__ __launch_bounds__(256) void k_mgemm(
    const u16* __restrict__ Ah,
    const u16* __restrict__ Bh, const u16* __restrict__ Bl,
    const float* __restrict__ bias, const float* __restrict__ bias1,
    const float* __restrict__ bias2,
    float* __restrict__ C, float* __restrict__ C1, float* __restrict__ C2,
    u16* __restrict__ Ch,
    int M, int N, int K, int Lc,
    const float* __restrict__ p_m, const float* __restrict__ p_v,
    const float* __restrict__ p_g, const float* __restrict__ p_b) {
  __shared__ __align__(16) u16 As[4096], Bs_h[4096], Bs_l[4096];
  const int tid = threadIdx.x;
  const int m0 = blockIdx.y * 128, n0 = blockIdx.x * 128;
  const int wid = tid >> 6, lane = tid & 63;
  const int wm = (wid & 1) * 64, wn = (wid >> 1) * 64;
  const int lr = lane >> 4, lc = lane & 15;
  f32x4 acc[4][4], acc2[4][4];
  f32x4 zz = {0.f, 0.f, 0.f, 0.f};
#pragma unroll
  for (int i = 0; i < 4; i++)
#pragma unroll
    for (int j = 0; j < 4; j++) { acc[i][j] = zz; acc2[i][j] = zz; }

  for (int k0 = 0; k0 < K; k0 += 32) {
#pragma unroll
    for (int pass = 0; pass < 2; pass++) {
      int c = tid + pass * 256;
      int mi = c >> 2, kc = (c & 3) * 8;
      size_t asrc;
      if (CONV) {
        int m = m0 + mi;
        int b = m >> 11, t = m & (LL1 - 1);
        int kblk = k0 >> 9;
        int srow = (b << 11) + ((t + kblk - 1 + LL1) & (LL1 - 1));
        asrc = (size_t)srow * 512 + (k0 - (kblk << 9)) + kc;
      } else {
        asrc = (size_t)(m0 + mi) * K + k0 + kc;
      }
      size_t bsrc = (size_t)(n0 + mi) * K + k0 + kc;
      u32 ldo = (u32)((wid * 64 + pass * 256) * 8);
      GLD16(Ah + asrc, As + ldo);
      GLD16(Bh + bsrc, Bs_h + ldo);
      GLD16(Bl + bsrc, Bs_l + ldo);
    }
    __syncthreads();
    half8 av[4], bh[4], bl[4];
#pragma unroll
    for (int i = 0; i < 4; i++) {
      int ar = (wm + i * 16 + lc) * 32 + lr * 8;
      int br = (wn + i * 16 + lc) * 32 + lr * 8;
      av[i] = *(const half8*)&As[ar];
      bh[i] = *(const half8*)&Bs_h[br];
      bl[i] = *(const half8*)&Bs_l[br];
    }
#pragma unroll
    for (int i = 0; i < 4; i++)
#pragma unroll
      for (int j = 0; j < 4; j++) {
        acc[i][j] = __builtin_amdgcn_mfma_f32_16x16x32_f16(av[i], bh[j], acc[i][j], 0, 0, 0);
        acc2[i][j] = __builtin_amdgcn_mfma_f32_16x16x32_f16(av[i], bl[j], acc2[i][j], 0, 0, 0);
      }
    __syncthreads();
  }
#pragma unroll
  for (int j = 0; j < 4; j++) {
    int col = n0 + wn + j * 16 + lc;
    const float* bp = bias;
    float* Cp = C;
    int cw = col, Nw = N;
    if (MULTI) {
      int sel = col >> 9;
      bp = sel == 0 ? bias : (sel == 1 ? bias1 : bias2);
      Cp = sel == 0 ? C : (sel == 1 ? C1 : C2);
      cw = col & 511;
      Nw = 512;
    }
    float bs = bp[cw];
    float bnA = 0.f, bnB = 0.f;
    if (EPI == 2) {
      bnA = rsqrtf(p_v[cw] + 1e-5f) * p_g[cw];
      bnB = p_b[cw] - p_m[cw] * bnA;
    }
#pragma unroll
    for (int i = 0; i < 4; i++) {
#pragma unroll
      for (int q = 0; q < 4; q++) {
        int row = m0 + wm + i * 16 + lr * 4 + q;
        float t = fmaf(acc2[i][j][q], 0.0009765625f, acc[i][j][q]) + bs;
        if (EPI == 1) t = 0.5f * t * (1.0f + erff(t * 0.7071067811865475f));
        if (EPI == 2) { t = t * bnA + bnB; t = t > 0.f ? t : expm1f(t); }
        size_t o = (size_t)row * Nw + cw;
        if (OSINGLE) {
          Ch[o] = f2h(t);
        } else {
          Cp[o] = t;
        }
      }
    }
  }
}

// ---------------- fused weight split/transpose (fp16 hi + lo*1024) ---------
// WATT layout per layer l: [qh kh vh oh][ql kl vl ol] (each 512x512).
__global__ void k_splitall(const float* __restrict__ wq, const float* __restrict__ wk,
                           const float* __restrict__ wv, const float* __restrict__ wo,
                           const float* __restrict__ w1, const float* __restrict__ w2,
                           const float* __restrict__ cw,
                           u16* __restrict__ WATT, u16* __restrict__ W1T,
                           u16* __restrict__ W2T, u16* __restrict__ CWT) {
  int job = blockIdx.y;
  int g = blockIdx.x * 256 + threadIdx.x;
  float v;
  u16 *dh, *dl;
  if (job < 8) {
    if (g >= 262144) return;
    int l = job >> 2, mi = job & 3;
    const float* src = (mi == 0 ? wq : mi == 1 ? wk : mi == 2 ? wv : wo) + (size_t)l * 262144;
    int n = g >> 9, k = g & 511;
    v = src[(size_t)k * 512 + n];
    dh = WATT + (size_t)(l * 8 + mi) * 262144;
    dl = dh + 4 * 262144;
  } else if (job == 8 || job == 10) {           // w1: K=512, N=2048
    if (g >= 1048576) return;
    int l = (job == 10);
    int n = g >> 9, k = g & 511;
    v = w1[(size_t)l * 1048576 + (size_t)k * 2048 + n];
    dh = W1T + (size_t)(l * 2) * 1048576;
    dl = dh + 1048576;
  } else if (job == 9 || job == 11) {           // w2: K=2048, N=512
    if (g >= 1048576) return;
    int l = (job == 11);
    int n = g >> 11, k = g & 2047;
    v = w2[(size_t)l * 1048576 + (size_t)k * 512 + n];
    dh = W2T + (size_t)(l * 2) * 1048576;
    dl = dh + 1048576;
  } else {                                       // conv
    if (g >= 786432) return;
    int c = g / 1536, k = g - c * 1536;
    int kblk = k >> 9, ci = k & 511;
    v = cw[c * 1536 + ci * 3 + kblk];
    dh = CWT;
    dl = CWT + 786432;
  }
  float wh = (float)(_Float16)v;
  dh[g] = f2h(v);
  dl[g] = f2h((v - wh) * 1024.0f);
}

// ---------------- sampled qk -> sparsity measure M -------------------------
__global__ void k_qk_m(const float* __restrict__ Q, const float* __restrict__ Km,
                       const int* __restrict__ idx, float* __restrict__ Mout,
                       int Lc, int u) {
  int row = blockIdx.x;
  int b = row / Lc, l = row - b * Lc;
  int tid = threadIdx.x;
  int nt = blockDim.x;
  __shared__ __align__(16) float qlds[DMODEL];
  __shared__ int ilds[40];
  __shared__ float qk[320];
  for (int i = tid; i < DMODEL; i += nt) qlds[i] = Q[(size_t)row * DMODEL + i];
  for (int i = tid; i < u; i += nt) ilds[i] = idx[l * u + i];
  __syncthreads();
  int tot = NHEADS * u;
  if (tid < tot) {
    int j = tid >> 3, h = tid & 7;
    int key = ilds[j];
    const float4* kp = reinterpret_cast<const float4*>(&Km[((size_t)b * Lc + key) * DMODEL + h * DKH]);
    const float4* qp = reinterpret_cast<const float4*>(&qlds[h * DKH]);
    float s = 0.f;
#pragma unroll
    for (int d = 0; d < 16; d++) {
      float4 kv = kp[d], qv = qp[d];
      s += qv.x * kv.x + qv.y * kv.y + qv.z * kv.z + qv.w * kv.w;
    }
    qk[tid] = s;
  }
  __syncthreads();
  if (tid < NHEADS) {
    int h = tid;
    float mx = -INFINITY, sm = 0.f;
    for (int j = 0; j < u; j++) {
      float v = qk[(j << 3) + h];
      mx = fmaxf(mx, v);
      sm += v;
    }
    Mout[((size_t)b * NHEADS + h) * Lc + l] = mx - sm / (float)Lc;
  }
}

// ---------------- top-u: register-resident tournament ----------------------
__global__ void k_topk(const float* __restrict__ Mv, int* __restrict__ mtop,
                       int Lc, int u) {
  int bh = blockIdx.x;
  int tid = threadIdx.x;
  int lane = tid & 63, wv = tid >> 6;
  __shared__ u64 wred[4];
  const int nk = Lc >> 8;
  u64 kk[8];
#pragma unroll
  for (int e = 0; e < 8; e++) {
    u64 key = 0;
    if (e < nk) {
      int i = e * 256 + tid;
      u32 ub = __builtin_bit_cast(u32, Mv[(size_t)bh * Lc + i]);
      ub = (ub & 0x80000000u) ? ~ub : (ub | 0x80000000u);
      key = ((u64)ub << 32) | (u64)(0xFFFFFFFFu - (u32)i);
    }
    kk[e] = key;
  }
  u64 lm = kk[0];
#pragma unroll
  for (int e = 1; e < 8; e++) lm = lm > kk[e] ? lm : kk[e];
  for (int it = 0; it < u; it++) {
    u64 best = lm;
#pragma unroll
    for (int o = 32; o > 0; o >>= 1) {
      u64 other = __shfl_xor(best, o);
      best = best > other ? best : other;
    }
    if (lane == 0) wred[wv] = best;
    __syncthreads();
    u64 b01 = wred[0] > wred[1] ? wred[0] : wred[1];
    u64 b23 = wred[2] > wred[3] ? wred[2] : wred[3];
    u64 b0 = b01 > b23 ? b01 : b23;
    int bi = (int)(0xFFFFFFFFu - (u32)(b0 & 0xFFFFFFFFull));
    if (tid == 0) mtop[bh * u + it] = bi;
    int s = bi & 255, e = bi >> 8;
    if (tid == s) {
#pragma unroll
      for (int e2 = 0; e2 < 8; e2++)
        if (e2 == e) kk[e2] = 0;
      lm = kk[0];
#pragma unroll
      for (int e2 = 1; e2 < 8; e2++) lm = lm > kk[e2] ? lm : kk[e2];
    }
    __syncthreads();
  }
}

// ---------------- column-sum two-phase -------------------------------------
__global__ void k_colsum1(const float* __restrict__ src, float* __restrict__ part,
                          int Lc, int rp) {
  int b = blockIdx.x, ch = blockIdx.y, c = threadIdx.x;
  const float* p = src + ((size_t)b * Lc + (size_t)ch * rp) * 512 + c;
  float s = 0.f;
  for (int r = 0; r < rp; r++) s += p[(size_t)r * 512];
  part[((b << 5) + ch) * 512 + c] = s;
}
__global__ void k_colsum2(const float* __restrict__ part, float* __restrict__ of,
                          u16* __restrict__ oh, int nch, float scale) {
  int b = blockIdx.x, c = threadIdx.x;
  float s = 0.f;
  for (int i = 0; i < nch; i++) s += part[(b * nch + i) * 512 + c];
  s *= scale;
  if (of) of[b * 512 + c] = s;
  if (oh) oh[b * 512 + c] = f2h(s);
}

// ---------------- fill context (fp16) with V-mean --------------------------
__global__ void k_ctx_fillb(u16* __restrict__ ch, const u16* __restrict__ vh,
                            int Lc) {
  int g = blockIdx.x * 256 + threadIdx.x;
  int total = BATCH * Lc * 128;
  if (g >= total) return;
  int c4 = g & 127;
  int row = g >> 7;
  int b = row / Lc;
  ((ushort4*)ch)[g] = ((const ushort4*)vh)[b * 128 + c4];
}

// ---------------- attention: 5 queries per block + scatter -----------------
// Block index: blk = qb*64 + bh so all qb-blocks of a (b,h) share an XCD
// (XCD = blk%8 = bh%8) -> K/V head slices become L2-resident across reuse.
__global__ __launch_bounds__(256) void k_attn_mq(
    const float* __restrict__ Q, const float* __restrict__ Km,
    const float* __restrict__ V, const int* __restrict__ mtop,
    u16* __restrict__ ctxh, int Lc, int u, int nqb) {
  int blk = blockIdx.x;
  int bh = blk & 63;
  int qb = blk >> 6;
  int h = bh & 7, b = bh >> 3;
  int tid = threadIdx.x;
  int lane = tid & 63, wv = tid >> 6;
  __shared__ __align__(16) float qlds[5][64];
  __shared__ float s_lds[5][2048];
  __shared__ float wredA[4], wredB[4];
  __shared__ int rows_s[5];
  __shared__ float part[4][5][64];
  for (int qq = tid; qq < 320; qq += 256) {
    int q = qq >> 6, d = qq & 63;
    int row = mtop[(b * 8 + h) * u + qb * 5 + q];
    if (d == 0) rows_s[q] = row;
    qlds[q][d] = Q[((size_t)b * Lc + row) * DMODEL + h * DKH + d];
  }
  __syncthreads();
  for (int k = tid; k < Lc; k += 256) {
    const float4* kp = reinterpret_cast<const float4*>(&Km[((size_t)b * Lc + k) * DMODEL + h * DKH]);
    float s0 = 0, s1 = 0, s2 = 0, s3 = 0, s4 = 0;
#pragma unroll
    for (int d = 0; d < 16; d++) {
      float4 kv = kp[d];
      float4 q0 = ((const float4*)qlds[0])[d];
      float4 q1 = ((const float4*)qlds[1])[d];
      float4 q2 = ((const float4*)qlds[2])[d];
      float4 q3 = ((const float4*)qlds[3])[d];
      float4 q4 = ((const float4*)qlds[4])[d];
      s0 += q0.x * kv.x + q0.y * kv.y + q0.z * kv.z + q0.w * kv.w;
      s1 += q1.x * kv.x + q1.y * kv.y + q1.z * kv.z + q1.w * kv.w;
      s2 += q2.x * kv.x + q2.y * kv.y + q2.z * kv.z + q2.w * kv.w;
      s3 += q3.x * kv.x + q3.y * kv.y + q3.z * kv.z + q3.w * kv.w;
      s4 += q4.x * kv.x + q4.y * kv.y + q4.z * kv.z + q4.w * kv.w;
    }
    s_lds[0][k] = s0 * 0.125f;
    s_lds[1][k] = s1 * 0.125f;
    s_lds[2][k] = s2 * 0.125f;
    s_lds[3][k] = s3 * 0.125f;
    s_lds[4][k] = s4 * 0.125f;
  }
  __syncthreads();
  float denomv[5];
#pragma unroll
  for (int q = 0; q < 5; q++) {
    float mx = -INFINITY;
    for (int k = tid; k < Lc; k += 256) mx = fmaxf(mx, s_lds[q][k]);
#pragma unroll
    for (int o = 32; o > 0; o >>= 1) mx = fmaxf(mx, __shfl_xor(mx, o));
    if (lane == 0) wredA[wv] = mx;
    __syncthreads();
    mx = fmaxf(fmaxf(wredA[0], wredA[1]), fmaxf(wredA[2], wredA[3]));
    float ls = 0.f;
    for (int k = tid; k < Lc; k += 256) {
      float w = expf(s_lds[q][k] - mx);
      s_lds[q][k] = w;
      ls += w;
    }
#pragma unroll
    for (int o = 32; o > 0; o >>= 1) ls += __shfl_xor(ls, o);
    if (lane == 0) wredB[wv] = ls;
    __syncthreads();
    denomv[q] = (wredB[0] + wredB[1]) + (wredB[2] + wredB[3]);
  }
  float acc0 = 0, acc1 = 0, acc2 = 0, acc3 = 0, acc4 = 0;
  int chunk = Lc >> 2;
  for (int k = wv * chunk; k < (wv + 1) * chunk; k++) {
    float vvv = V[((size_t)b * Lc + k) * DMODEL + h * DKH + lane];
    acc0 = fmaf(s_lds[0][k], vvv, acc0);
    acc1 = fmaf(s_lds[1][k], vvv, acc1);
    acc2 = fmaf(s_lds[2][k], vvv, acc2);
    acc3 = fmaf(s_lds[3][k], vvv, acc3);
    acc4 = fmaf(s_lds[4][k], vvv, acc4);
  }
  part[wv][0][lane] = acc0;
  part[wv][1][lane] = acc1;
  part[wv][2][lane] = acc2;
  part[wv][3][lane] = acc3;
  part[wv][4][lane] = acc4;
  __syncthreads();
  for (int q = wv; q < 5; q += 4) {
    float tot = ((part[0][q][lane] + part[1][q][lane]) +
                 (part[2][q][lane] + part[3][q][lane])) / denomv[q];
    size_t o = ((size_t)b * Lc + rows_s[q]) * DMODEL + h * DKH + lane;
    ctxh[o] = f2h(tot);
  }
}

// ---------------- y = LayerNorm(x+a)*g+b ; fp32 opt + fp16 out -------------
__global__ void k_add_ln(const float* __restrict__ x, const float* __restrict__ a,
                         const float* __restrict__ g, const float* __restrict__ be,
                         float* __restrict__ y, u16* __restrict__ yh) {
  int row = blockIdx.x;
  int tid = threadIdx.x;
  __shared__ float red[256];
  float2 xv = reinterpret_cast<const float2*>(x)[(size_t)row * 256 + tid];
  float2 av = reinterpret_cast<const float2*>(a)[(size_t)row * 256 + tid];
  float vx = xv.x + av.x, vy = xv.y + av.y;
  red[tid] = vx + vy;
  __syncthreads();
  for (int s = 128; s > 0; s >>= 1) {
    if (tid < s) red[tid] += red[tid + s];
    __syncthreads();
  }
  float mean = red[0] * (1.0f / 512.0f);
  __syncthreads();
  float dx = vx - mean, dy = vy - mean;
  red[tid] = dx * dx + dy * dy;
  __syncthreads();
  for (int s = 128; s > 0; s >>= 1) {
    if (tid < s) red[tid] += red[tid + s];
    __syncthreads();
  }
  float rstd = rsqrtf(red[0] * (1.0f / 512.0f) + 1e-5f);
  int c = tid * 2;
  float ox = dx * rstd * g[c] + be[c];
  float oy = dy * rstd * g[c + 1] + be[c + 1];
  if (y) {
    float2 o = {ox, oy};
    reinterpret_cast<float2*>(y)[(size_t)row * 256 + tid] = o;
  }
  if (yh) {
    size_t base = (size_t)row * 512 + c;
    yh[base] = f2h(ox);
    yh[base + 1] = f2h(oy);
  }
}

// ---------------- maxpool k=3 s=2, fp32 + fp16 out -------------------------
__global__ void k_pool(const float* __restrict__ cv, float* __restrict__ out,
                       u16* __restrict__ oh) {
  int g = blockIdx.x * 256 + threadIdx.x;
  int total = BATCH * LL2 * DMODEL;
  if (g >= total) return;
  int c = g & 511;
  int rest = g >> 9;
  int i = rest & (LL2 - 1);
  int b = rest >> 10;
  int t0 = 2 * i - 1;
  float m = -INFINITY;
#pragma unroll
  for (int k = 0; k < 3; k++) {
    int t = t0 + k;
    if (t >= 0 && t < LL1) m = fmaxf(m, cv[((size_t)b * LL1 + t) * DMODEL + c]);
  }
  out[g] = m;
  oh[g] = f2h(m);
}

// ---------------- gx = enc @ wih^T + bih (+ zero lstm tag buffer) ----------
__global__ void k_gx(const float* __restrict__ enc, const float* __restrict__ wih,
                     const float* __restrict__ bih, float* __restrict__ gx,
                     u64* __restrict__ hgl) {
  int g = blockIdx.x * 256 + threadIdx.x;
  if (g < 8192) hgl[g] = 0ull;
  if (g >= BATCH * 2048) return;
  int b = g >> 11, j = g & 2047;
  const float4* wp = reinterpret_cast<const float4*>(&wih[(size_t)j * 512]);
  const float4* ep = reinterpret_cast<const float4*>(&enc[b * 512]);
  float s = bih[j];
  for (int d = 0; d < 128; d++) {
    float4 w = wp[d], e = ep[d];
    s += w.x * e.x + w.y * e.y + w.z * e.z + w.w * e.w;
  }
  gx[g] = s;
}

// ---------------- persistent LSTM v5: tagged-u64 single-RT exchange --------
__global__ __launch_bounds__(256, 1) void k_lstm5(
    const float* __restrict__ gx, const float* __restrict__ whh,
    const float* __restrict__ bhh, const float* __restrict__ ow,
    const float* __restrict__ ob, float* __restrict__ out,
    u64* __restrict__ hglob) {
  const int bl = blockIdx.x, tid = threadIdx.x;
  const int part = tid >> 5, idx = tid & 31;
  const int gtype = idx >> 3, ml = idx & 7;
  const int j = gtype * 512 + bl * 8 + ml;
  __shared__ float h_s[4096];
  __shared__ float red[8][8][32];
  __shared__ float gvs[8][32];
  __shared__ float ow_s[512];
  __shared__ float ored[4];
  float w[64];
  {
    const float* wr = &whh[(size_t)j * 512 + part * 64];
#pragma unroll
    for (int r = 0; r < 64; r += 4) {
      float4 v = *(const float4*)&wr[r];
      w[r] = v.x; w[r + 1] = v.y; w[r + 2] = v.z; w[r + 3] = v.w;
    }
  }
  const float gxrow = gx[part * 2048 + j] + bhh[j];
  float cst = 0.f;
  for (int i = tid; i < 4096; i += 256) h_s[i] = 0.f;
  for (int i = tid; i < 512; i += 256) ow_s[i] = ow[i];
  const float obv = ob[0];
  __syncthreads();
  for (int t = 0; t < TPRED; t++) {
    float p[8];
#pragma unroll
    for (int b = 0; b < 8; b++) p[b] = 0.f;
#pragma unroll
    for (int r = 0; r < 64; r += 4) {
      float w0 = w[r], w1 = w[r + 1], w2 = w[r + 2], w3 = w[r + 3];
#pragma unroll
      for (int b = 0; b < 8; b++) {
        float4 hv = *(const float4*)&h_s[b * 512 + part * 64 + r];
        p[b] = fmaf(w3, hv.w, fmaf(w2, hv.z, fmaf(w1, hv.y, fmaf(w0, hv.x, p[b]))));
      }
    }
#pragma unroll
    for (int b = 0; b < 8; b++) red[b][part][idx] = p[b];
    __syncthreads();
    float gv = gxrow;
#pragma unroll
    for (int pp = 0; pp < 8; pp++) gv += red[part][pp][idx];
    gvs[part][idx] = gv;
    __syncthreads();
    u64* hgb = hglob + ((t + 1) & 1) * 4096;
    const u32 want = (u32)(t + 1);
    if (tid < 64) {
      int b = tid >> 3, m = tid & 7;
      float gi = gvs[b][m], gf = gvs[b][8 + m];
      float gg = gvs[b][16 + m], go = gvs[b][24 + m];
      float c = sigm(gf) * cst + sigm(gi) * tanhf(gg);
      cst = c;
      float hn = sigm(go) * tanhf(c);
      u64 word = ((u64)want << 32) | (u64)__builtin_bit_cast(u32, hn);
      __hip_atomic_store(&hgb[b * 512 + bl * 8 + m], word, __ATOMIC_RELAXED,
                         __HIP_MEMORY_SCOPE_AGENT);
    }
    {
      u64 v[16];
#pragma unroll
      for (int q = 0; q < 16; q++)
        v[q] = __hip_atomic_load(&hgb[q * 256 + tid], __ATOMIC_RELAXED,
                                 __HIP_MEMORY_SCOPE_AGENT);
      bool ok;
      do {
        ok = true;
#pragma unroll
        for (int q = 0; q < 16; q++) {
          if ((u32)(v[q] >> 32) != want) {
            ok = false;
            v[q] = __hip_atomic_load(&hgb[q * 256 + tid], __ATOMIC_RELAXED,
                                     __HIP_MEMORY_SCOPE_AGENT);
          }
        }
      } while (!ok);
#pragma unroll
      for (int q = 0; q < 16; q++)
        h_s[q * 256 + tid] = __builtin_bit_cast(float, (u32)(v[q] & 0xFFFFFFFFull));
    }
    __syncthreads();
    if (bl < 8) {
      float s = h_s[bl * 512 + tid] * ow_s[tid] +
                h_s[bl * 512 + 256 + tid] * ow_s[256 + tid];
#pragma unroll
      for (int o = 32; o > 0; o >>= 1) s += __shfl_xor(s, o);
      if ((tid & 63) == 0) ored[tid >> 6] = s;
      __syncthreads();
      if (tid == 0)
        out[bl * TPRED + t] = (ored[0] + ored[1]) + (ored[2] + ored[3]) + obv;
    }
  }
}

// ---------------------------------------------------------------------------
extern "C" void kernel_launch(void* const* d_in, const int* in_sizes, int n_in,
                              void* d_out, int out_size, void* d_ws, size_t ws_size,
                              hipStream_t stream) {
  const float* x = (const float*)d_in[0];
  const int* idx1 = (const int*)d_in[1];
  const int* idx2 = (const int*)d_in[2];
  const float* emb_w = (const float*)d_in[3];
  const float* emb_b = (const float*)d_in[4];
  const float* wq = (const float*)d_in[5];
  const float* bq = (const float*)d_in[6];
  const float* wk = (const float*)d_in[7];
  const float* bk = (const float*)d_in[8];
  const float* wv = (const float*)d_in[9];
  const float* bv = (const float*)d_in[10];
  const float* wo = (const float*)d_in[11];
  const float* bo = (const float*)d_in[12];
  const float* w1 = (const float*)d_in[13];
  const float* b1 = (const float*)d_in[14];
  const float* w2 = (const float*)d_in[15];
  const float* b2 = (const float*)d_in[16];
  const float* ln1g = (const float*)d_in[17];
  const float* ln1b = (const float*)d_in[18];
  const float* ln2g = (const float*)d_in[19];
  const float* ln2b = (const float*)d_in[20];
  const float* conv_w = (const float*)d_in[21];
  const float* conv_b = (const float*)d_in[22];
  const float* bn_g = (const float*)d_in[23];
  const float* bn_b = (const float*)d_in[24];
  const float* bn_m = (const float*)d_in[25];
  const float* bn_v = (const float*)d_in[26];
  const float* lstm_wih = (const float*)d_in[27];
  const float* lstm_whh = (const float*)d_in[28];
  const float* lstm_bih = (const float*)d_in[29];
  const float* lstm_bhh = (const float*)d_in[30];
  const float* out_w = (const float*)d_in[31];
  const float* out_b = (const float*)d_in[32];
  float* outp = (float*)d_out;

  char* ws = (char*)d_ws;
  const size_t MB = 1 << 20;
  float* S0 = (float*)(ws);
  float* S1 = (float*)(ws + 32 * MB);
  float* S2 = (float*)(ws + 64 * MB);
  float* S3 = (float*)(ws + 96 * MB);
  u16* P0 = (u16*)(ws + 128 * MB);
  u16* P1 = (u16*)(ws + 144 * MB);
  u16* P2 = (u16*)(ws + 160 * MB);
  u16* P3 = (u16*)(ws + 176 * MB);
  u16* WATT = (u16*)(ws + 192 * MB);
  u16* W1T = (u16*)(ws + 200 * MB);
  u16* W2T = (u16*)(ws + 208 * MB);
  u16* CWT = (u16*)(ws + 216 * MB);
  char* SMB = ws + 220 * MB;
  float* Mbuf = (float*)(SMB);
  float* csp = (float*)(SMB + 512 * 1024);
  u16* vmh = (u16*)(SMB + 1040 * 1024);
  int* mtop = (int*)(SMB + 1056 * 1024);
  float* gxb = (float*)(SMB + 1088 * 1024);
  float* encb = (float*)(SMB + 1152 * 1024);
  u64* hglob = (u64*)(SMB + 1168 * 1024);

  auto wat = [&](int l, int m, int hl) {
    return WATT + ((size_t)(l * 8 + hl * 4 + m)) * 262144;
  };

  // fused weight split (single dispatch)
  {
    dim3 g(4096, 13);
    k_splitall<<<g, 256, 0, stream>>>(wq, wk, wv, wo, w1, w2, conv_w,
                                      WATT, W1T, W2T, CWT);
  }

  auto mg = [&](const u16* Ah, const u16* Bh, const u16* Bl,
                const float* bias, float* C, int M, int N, int K) {
    dim3 g(N / 128, M / 128);
    k_mgemm<0, 0, 0, 0><<<g, 256, 0, stream>>>(
        Ah, Bh, Bl, bias, nullptr, nullptr, C, nullptr, nullptr,
        nullptr, M, N, K, 0, nullptr, nullptr, nullptr, nullptr);
  };
  auto mg3 = [&](const u16* Ah, const u16* Bh, const u16* Bl,
                 const float* b0_, const float* b1_, const float* b2_,
                 float* C0_, float* C1_, float* C2_, int M) {
    dim3 g(12, M / 128);
    k_mgemm<0, 0, 0, 1><<<g, 256, 0, stream>>>(
        Ah, Bh, Bl, b0_, b1_, b2_, C0_, C1_, C2_,
        nullptr, M, 1536, 512, 0, nullptr, nullptr, nullptr, nullptr);
  };

  // ---------------- embed ----------------
  k_embed<<<(BATCH * LL1) / 8, 256, 0, stream>>>(x, emb_w, emb_b, S0, P0);

  // ---------------- encoder layer 1 (L=2048, u=40) ----------------
  {
    const int Lc = LL1, u = 40, M = BATCH * LL1;
    mg3(P0, wat(0, 0, 0), wat(0, 0, 1), bq, bk, bv, S1, S2, S3, M);
    k_qk_m<<<M, 320, 0, stream>>>(S1, S2, idx1, Mbuf, Lc, u);
    k_topk<<<64, 256, 0, stream>>>(Mbuf, mtop, Lc, u);
    k_colsum1<<<dim3(BATCH, 32), 512, 0, stream>>>(S3, csp, Lc, Lc / 32);
    k_colsum2<<<BATCH, 512, 0, stream>>>(csp, nullptr, vmh, 32, 1.f / Lc);
    k_ctx_fillb<<<(BATCH * Lc * 128) / 256, 256, 0, stream>>>(P2, vmh, Lc);
    k_attn_mq<<<64 * 8, 256, 0, stream>>>(S1, S2, S3, mtop, P2, Lc, u, 8);
    mg(P2, wat(0, 3, 0), wat(0, 3, 1), bo, S1, M, 512, 512);
    k_add_ln<<<M, 256, 0, stream>>>(S0, S1, ln1g, ln1b, S2, P0);
    u16* hidh = (u16*)S0;
    for (int c = 0; c < 2; c++) {
      dim3 g1(16, 64);
      k_mgemm<1, 0, 1, 0><<<g1, 256, 0, stream>>>(
          P0 + (size_t)c * 8192 * 512, W1T, W1T + 1048576, b1,
          nullptr, nullptr, nullptr, nullptr, nullptr,
          hidh, 8192, 2048, 512, 0, nullptr, nullptr, nullptr, nullptr);
      dim3 g2(4, 64);
      k_mgemm<0, 0, 0, 0><<<g2, 256, 0, stream>>>(
          hidh, W2T, W2T + 1048576, b2, nullptr, nullptr,
          S3 + (size_t)c * 8192 * 512, nullptr, nullptr, nullptr,
          8192, 512, 2048, 0, nullptr, nullptr, nullptr, nullptr);
    }
    k_add_ln<<<M, 256, 0, stream>>>(S2, S3, ln2g, ln2b, nullptr, P0);
  }

  // ---------------- conv distill ----------------
  {
    dim3 g(4, 128);
    k_mgemm<2, 1, 0, 0><<<g, 256, 0, stream>>>(
        P0, CWT, CWT + 786432, conv_b, nullptr, nullptr,
        S1, nullptr, nullptr, nullptr, 16384, 512, 1536,
        LL1, bn_m, bn_v, bn_g, bn_b);
    k_pool<<<(BATCH * LL2 * 512) / 256, 256, 0, stream>>>(S1, S2, P0);
  }

  // ---------------- encoder layer 2 (L=1024, u=35) ----------------
  {
    const int Lc = LL2, u = 35, M = BATCH * LL2;
    float* Qb = S1;
    float* Kb = S1 + 4194304;
    float* Vb = S3;
    float* AOb = S3 + 4194304;
    mg3(P0, wat(1, 0, 0), wat(1, 0, 1), bq + 512, bk + 512, bv + 512,
        Qb, Kb, Vb, M);
    k_qk_m<<<M, 320, 0, stream>>>(Qb, Kb, idx2, Mbuf, Lc, u);
    k_topk<<<64, 256, 0, stream>>>(Mbuf, mtop, Lc, u);
    k_colsum1<<<dim3(BATCH, 32), 512, 0, stream>>>(Vb, csp, Lc, Lc / 32);
    k_colsum2<<<BATCH, 512, 0, stream>>>(csp, nullptr, vmh, 32, 1.f / Lc);
    k_ctx_fillb<<<(BATCH * Lc * 128) / 256, 256, 0, stream>>>(P2, vmh, Lc);
    k_attn_mq<<<64 * 7, 256, 0, stream>>>(Qb, Kb, Vb, mtop, P2, Lc, u, 7);
    mg(P2, wat(1, 3, 0), wat(1, 3, 1), bo + 512, AOb, M, 512, 512);
    k_add_ln<<<M, 256, 0, stream>>>(S2, AOb, ln1g + 512, ln1b + 512, S0, P0);
    u16* hidh = (u16*)S1;
    {
      dim3 g1(16, 64);
      k_mgemm<1, 0, 1, 0><<<g1, 256, 0, stream>>>(
          P0, W1T + (size_t)2 * 1048576, W1T + (size_t)3 * 1048576,
          b1 + 2048, nullptr, nullptr, nullptr, nullptr, nullptr,
          hidh, 8192, 2048, 512, 0, nullptr, nullptr, nullptr, nullptr);
      dim3 g2(4, 64);
      k_mgemm<0, 0, 0, 0><<<g2, 256, 0, stream>>>(
          hidh, W2T + (size_t)2 * 1048576, W2T + (size_t)3 * 1048576,
          b2 + 512, nullptr, nullptr, S2, nullptr, nullptr, nullptr,
          8192, 512, 2048, 0, nullptr, nullptr, nullptr, nullptr);
    }
    k_add_ln<<<M, 256, 0, stream>>>(S0, S2, ln2g + 512, ln2b + 512, S3, nullptr);
  }

  // ---------------- mean -> LSTM -> output ----------------
  k_colsum1<<<dim3(BATCH, 32), 512, 0, stream>>>(S3, csp, LL2, LL2 / 32);
  k_colsum2<<<BATCH, 512, 0, stream>>>(csp, encb, nullptr, 32, 1.f / LL2);
  k_gx<<<(BATCH * 2048) / 256, 256, 0, stream>>>(encb, lstm_wih, lstm_bih, gxb, hglob);
  k_lstm5<<<64, 256, 0, stream>>>(gxb, lstm_whh, lstm_bhh, out_w, out_b, outp, hglob);
}

// Round 11
// 2342.978 us; speedup vs baseline: 1.0506x; 1.0506x over previous
//
#include <hip/hip_runtime.h>
#include <hip/hip_bf16.h>
#include <math.h>

static constexpr int BATCH = 8;
static constexpr int LL1 = 2048;
static constexpr int LL2 = 1024;
static constexpr int DMODEL = 512;
static constexpr int NHEADS = 8;
static constexpr int DKH = 64;
static constexpr int TPRED = 100;

typedef unsigned short u16;
typedef unsigned int u32;
typedef unsigned long long u64;
typedef __attribute__((ext_vector_type(8))) _Float16 half8;
typedef __attribute__((ext_vector_type(4))) float f32x4;

__device__ __forceinline__ float sigm(float x) { return 1.0f / (1.0f + expf(-x)); }

// fp16 helpers (RNE)
__device__ __forceinline__ u16 f2h(float f) {
  _Float16 h = (_Float16)f;
  return __builtin_bit_cast(u16, h);
}

#define GLD16(gsrc, ldst) __builtin_amdgcn_global_load_lds( \
    (const __attribute__((address_space(1))) u32*)(gsrc),   \
    (__attribute__((address_space(3))) u32*)(ldst), 16, 0, 0)

// ---------------- embedding + posenc, writes fp32 + fp16 -------------------
__global__ void k_embed(const float* __restrict__ x, const float* __restrict__ ew,
                        const float* __restrict__ eb, float* __restrict__ out,
                        u16* __restrict__ oh) {
  int r0 = blockIdx.x * 8;          // 2048 blocks
  int tid = threadIdx.x;            // 256
  __shared__ float xr[8][64];
  for (int i = tid; i < 512; i += 256)
    xr[i >> 6][i & 63] = x[(size_t)r0 * 64 + i];
  __syncthreads();
  const float fac = -9.210340371976184f / 512.0f;
  int l0 = r0 & (LL1 - 1);
  for (int c = tid; c < DMODEL; c += 256) {
    float acc[8];
#pragma unroll
    for (int r = 0; r < 8; r++) acc[r] = eb[c];
    for (int i = 0; i < 64; i++) {
      float w = ew[i * DMODEL + c];
#pragma unroll
      for (int r = 0; r < 8; r++) acc[r] = fmaf(xr[r][i], w, acc[r]);
    }
    float divv = expf((float)(2 * (c >> 1)) * fac);
#pragma unroll
    for (int r = 0; r < 8; r++) {
      float ang = (float)(l0 + r) * divv;
      float v = acc[r] + ((c & 1) ? cosf(ang) : sinf(ang));
      size_t o = (size_t)(r0 + r) * DMODEL + c;
      out[o] = v;
      oh[o] = f2h(v);
    }
  }
}

// ---------------- MFMA GEMM, fp16 act x fp16-split weights -----------------
// C = A@(Wh + Wl/1024) + bias. 2 MFMA/product via separate accumulators.
// 2-phase pipelined staging: tile t+1 loads issued BEFORE tile-t compute;
// single __syncthreads per iteration (its vmcnt(0) drain lands after compute
// -> load latency overlaps ds_read+MFMA). Double-buffered LDS (48KB).
template <int EPI, int CONV, int OSINGLE, int MULTI>
__global__ __launch_bounds__(256) void k_mgemm(
    const u16* __restrict__ Ah,
    const u16* __restrict__ Bh, const u16* __restrict__ Bl,
    const float* __restrict__ bias, const float* __restrict__ bias1,
    const float* __restrict__ bias2,
    float* __restrict__ C, float* __restrict__ C1, float* __restrict__ C2,
    u16* __restrict__ Ch,
    int M, int N, int K, int Lc,
    const float* __restrict__ p_m, const float* __restrict__ p_v,
    const float* __restrict__ p_g, const float* __restrict__ p_b) {
  __shared__ __align__(16) u16 As[2][4096], Bs_h[2][4096], Bs_l[2][4096];
  const int tid = threadIdx.x;
  const int m0 = blockIdx.y * 128, n0 = blockIdx.x * 128;
  const int wid = tid >> 6, lane = tid & 63;
  const int wm = (wid & 1) * 64, wn = (wid >> 1) * 64;
  const int lr = lane >> 4, lc = lane & 15;
  f32x4 acc[4][4], acc2[4][4];
  f32x4 zz = {0.f, 0.f, 0.f, 0.f};
#pragma unroll
  for (int i = 0; i < 4; i++)
#pragma unroll
    for (int j = 0; j < 4; j++) { acc[i][j] = zz; acc2[i][j] = zz; }

  auto stage = [&](int sb, int k0) {
#pragma unroll
    for (int pass = 0; pass < 2; pass++) {
      int c = tid + pass * 256;
      int mi = c >> 2, kc = (c & 3) * 8;
      size_t asrc;
      if (CONV) {
        int m = m0 + mi;
        int b = m >> 11, t = m & (LL1 - 1);
        int kblk = k0 >> 9;
        int srow = (b << 11) + ((t + kblk - 1 + LL1) & (LL1 - 1));
        asrc = (size_t)srow * 512 + (k0 - (kblk << 9)) + kc;
      } else {
        asrc = (size_t)(m0 + mi) * K + k0 + kc;
      }
      size_t bsrc = (size_t)(n0 + mi) * K + k0 + kc;
      u32 ldo = (u32)((wid * 64 + pass * 256) * 8);
      GLD16(Ah + asrc, &As[sb][ldo]);
      GLD16(Bh + bsrc, &Bs_h[sb][ldo]);
      GLD16(Bl + bsrc, &Bs_l[sb][ldo]);
    }
  };

  stage(0, 0);
  __syncthreads();
  int sb = 0;
  for (int k0 = 0; k0 < K; k0 += 32) {
    if (k0 + 32 < K) stage(sb ^ 1, k0 + 32);
    const u16* Ap = As[sb];
    const u16* Bhp = Bs_h[sb];
    const u16* Blp = Bs_l[sb];
    half8 av[4], bh[4], bl[4];
#pragma unroll
    for (int i = 0; i < 4; i++) {
      int ar = (wm + i * 16 + lc) * 32 + lr * 8;
      int br = (wn + i * 16 + lc) * 32 + lr * 8;
      av[i] = *(const half8*)&Ap[ar];
      bh[i] = *(const half8*)&Bhp[br];
      bl[i] = *(const half8*)&Blp[br];
    }
#pragma unroll
    for (int i = 0; i < 4; i++)
#pragma unroll
      for (int j = 0; j < 4; j++) {
        acc[i][j] = __builtin_amdgcn_mfma_f32_16x16x32_f16(av[i], bh[j], acc[i][j], 0, 0, 0);
        acc2[i][j] = __builtin_amdgcn_mfma_f32_16x16x32_f16(av[i], bl[j], acc2[i][j], 0, 0, 0);
      }
    __syncthreads();   // drains next-tile loads (overlapped with compute above)
    sb ^= 1;
  }
#pragma unroll
  for (int j = 0; j < 4; j++) {
    int col = n0 + wn + j * 16 + lc;
    const float* bp = bias;
    float* Cp = C;
    int cw = col, Nw = N;
    if (MULTI) {
      int sel = col >> 9;
      bp = sel == 0 ? bias : (sel == 1 ? bias1 : bias2);
      Cp = sel == 0 ? C : (sel == 1 ? C1 : C2);
      cw = col & 511;
      Nw = 512;
    }
    float bs = bp[cw];
    float bnA = 0.f, bnB = 0.f;
    if (EPI == 2) {
      bnA = rsqrtf(p_v[cw] + 1e-5f) * p_g[cw];
      bnB = p_b[cw] - p_m[cw] * bnA;
    }
#pragma unroll
    for (int i = 0; i < 4; i++) {
#pragma unroll
      for (int q = 0; q < 4; q++) {
        int row = m0 + wm + i * 16 + lr * 4 + q;
        float t = fmaf(acc2[i][j][q], 0.0009765625f, acc[i][j][q]) + bs;
        if (EPI == 1) t = 0.5f * t * (1.0f + erff(t * 0.7071067811865475f));
        if (EPI == 2) { t = t * bnA + bnB; t = t > 0.f ? t : expm1f(t); }
        size_t o = (size_t)row * Nw + cw;
        if (OSINGLE) {
          Ch[o] = f2h(t);
        } else {
          Cp[o] = t;
        }
      }
    }
  }
}

// ---------------- fused weight split/transpose (fp16 hi + lo*1024) ---------
__global__ void k_splitall(const float* __restrict__ wq, const float* __restrict__ wk,
                           const float* __restrict__ wv, const float* __restrict__ wo,
                           const float* __restrict__ w1, const float* __restrict__ w2,
                           const float* __restrict__ cw,
                           u16* __restrict__ WATT, u16* __restrict__ W1T,
                           u16* __restrict__ W2T, u16* __restrict__ CWT) {
  int job = blockIdx.y;
  int g = blockIdx.x * 256 + threadIdx.x;
  float v;
  u16 *dh, *dl;
  if (job < 8) {
    if (g >= 262144) return;
    int l = job >> 2, mi = job & 3;
    const float* src = (mi == 0 ? wq : mi == 1 ? wk : mi == 2 ? wv : wo) + (size_t)l * 262144;
    int n = g >> 9, k = g & 511;
    v = src[(size_t)k * 512 + n];
    dh = WATT + (size_t)(l * 8 + mi) * 262144;
    dl = dh + 4 * 262144;
  } else if (job == 8 || job == 10) {           // w1: K=512, N=2048
    if (g >= 1048576) return;
    int l = (job == 10);
    int n = g >> 9, k = g & 511;
    v = w1[(size_t)l * 1048576 + (size_t)k * 2048 + n];
    dh = W1T + (size_t)(l * 2) * 1048576;
    dl = dh + 1048576;
  } else if (job == 9 || job == 11) {           // w2: K=2048, N=512
    if (g >= 1048576) return;
    int l = (job == 11);
    int n = g >> 11, k = g & 2047;
    v = w2[(size_t)l * 1048576 + (size_t)k * 512 + n];
    dh = W2T + (size_t)(l * 2) * 1048576;
    dl = dh + 1048576;
  } else {                                       // conv
    if (g >= 786432) return;
    int c = g / 1536, k = g - c * 1536;
    int kblk = k >> 9, ci = k & 511;
    v = cw[c * 1536 + ci * 3 + kblk];
    dh = CWT;
    dl = CWT + 786432;
  }
  float wh = (float)(_Float16)v;
  dh[g] = f2h(v);
  dl[g] = f2h((v - wh) * 1024.0f);
}

// ---------------- sampled qk -> sparsity measure M -------------------------
__global__ void k_qk_m(const float* __restrict__ Q, const float* __restrict__ Km,
                       const int* __restrict__ idx, float* __restrict__ Mout,
                       int Lc, int u) {
  int row = blockIdx.x;
  int b = row / Lc, l = row - b * Lc;
  int tid = threadIdx.x;
  int nt = blockDim.x;
  __shared__ __align__(16) float qlds[DMODEL];
  __shared__ int ilds[40];
  __shared__ float qk[320];
  for (int i = tid; i < DMODEL; i += nt) qlds[i] = Q[(size_t)row * DMODEL + i];
  for (int i = tid; i < u; i += nt) ilds[i] = idx[l * u + i];
  __syncthreads();
  int tot = NHEADS * u;
  if (tid < tot) {
    int j = tid >> 3, h = tid & 7;
    int key = ilds[j];
    const float4* kp = reinterpret_cast<const float4*>(&Km[((size_t)b * Lc + key) * DMODEL + h * DKH]);
    const float4* qp = reinterpret_cast<const float4*>(&qlds[h * DKH]);
    float s = 0.f;
#pragma unroll
    for (int d = 0; d < 16; d++) {
      float4 kv = kp[d], qv = qp[d];
      s += qv.x * kv.x + qv.y * kv.y + qv.z * kv.z + qv.w * kv.w;
    }
    qk[tid] = s;
  }
  __syncthreads();
  if (tid < NHEADS) {
    int h = tid;
    float mx = -INFINITY, sm = 0.f;
    for (int j = 0; j < u; j++) {
      float v = qk[(j << 3) + h];
      mx = fmaxf(mx, v);
      sm += v;
    }
    Mout[((size_t)b * NHEADS + h) * Lc + l] = mx - sm / (float)Lc;
  }
}

// ---------------- top-u: register-resident tournament ----------------------
__global__ void k_topk(const float* __restrict__ Mv, int* __restrict__ mtop,
                       int Lc, int u) {
  int bh = blockIdx.x;
  int tid = threadIdx.x;
  int lane = tid & 63, wv = tid >> 6;
  __shared__ u64 wred[4];
  const int nk = Lc >> 8;
  u64 kk[8];
#pragma unroll
  for (int e = 0; e < 8; e++) {
    u64 key = 0;
    if (e < nk) {
      int i = e * 256 + tid;
      u32 ub = __builtin_bit_cast(u32, Mv[(size_t)bh * Lc + i]);
      ub = (ub & 0x80000000u) ? ~ub : (ub | 0x80000000u);
      key = ((u64)ub << 32) | (u64)(0xFFFFFFFFu - (u32)i);
    }
    kk[e] = key;
  }
  u64 lm = kk[0];
#pragma unroll
  for (int e = 1; e < 8; e++) lm = lm > kk[e] ? lm : kk[e];
  for (int it = 0; it < u; it++) {
    u64 best = lm;
#pragma unroll
    for (int o = 32; o > 0; o >>= 1) {
      u64 other = __shfl_xor(best, o);
      best = best > other ? best : other;
    }
    if (lane == 0) wred[wv] = best;
    __syncthreads();
    u64 b01 = wred[0] > wred[1] ? wred[0] : wred[1];
    u64 b23 = wred[2] > wred[3] ? wred[2] : wred[3];
    u64 b0 = b01 > b23 ? b01 : b23;
    int bi = (int)(0xFFFFFFFFu - (u32)(b0 & 0xFFFFFFFFull));
    if (tid == 0) mtop[bh * u + it] = bi;
    int s = bi & 255, e = bi >> 8;
    if (tid == s) {
#pragma unroll
      for (int e2 = 0; e2 < 8; e2++)
        if (e2 == e) kk[e2] = 0;
      lm = kk[0];
#pragma unroll
      for (int e2 = 1; e2 < 8; e2++) lm = lm > kk[e2] ? lm : kk[e2];
    }
    __syncthreads();
  }
}

// ---------------- column-sum two-phase -------------------------------------
__global__ void k_colsum1(const float* __restrict__ src, float* __restrict__ part,
                          int Lc, int rp) {
  int b = blockIdx.x, ch = blockIdx.y, c = threadIdx.x;
  const float* p = src + ((size_t)b * Lc + (size_t)ch * rp) * 512 + c;
  float s = 0.f;
  for (int r = 0; r < rp; r++) s += p[(size_t)r * 512];
  part[((b << 5) + ch) * 512 + c] = s;
}
__global__ void k_colsum2(const float* __restrict__ part, float* __restrict__ of,
                          u16* __restrict__ oh, int nch, float scale) {
  int b = blockIdx.x, c = threadIdx.x;
  float s = 0.f;
  for (int i = 0; i < nch; i++) s += part[(b * nch + i) * 512 + c];
  s *= scale;
  if (of) of[b * 512 + c] = s;
  if (oh) oh[b * 512 + c] = f2h(s);
}

// ---------------- fill context (fp16) with V-mean --------------------------
__global__ void k_ctx_fillb(u16* __restrict__ ch, const u16* __restrict__ vh,
                            int Lc) {
  int g = blockIdx.x * 256 + threadIdx.x;
  int total = BATCH * Lc * 128;
  if (g >= total) return;
  int c4 = g & 127;
  int row = g >> 7;
  int b = row / Lc;
  ((ushort4*)ch)[g] = ((const ushort4*)vh)[b * 128 + c4];
}

// ---------------- attention: 5 queries per block + scatter -----------------
__global__ __launch_bounds__(256) void k_attn_mq(
    const float* __restrict__ Q, const float* __restrict__ Km,
    const float* __restrict__ V, const int* __restrict__ mtop,
    u16* __restrict__ ctxh, int Lc, int u, int nqb) {
  int blk = blockIdx.x;
  int bh = blk & 63;
  int qb = blk >> 6;
  int h = bh & 7, b = bh >> 3;
  int tid = threadIdx.x;
  int lane = tid & 63, wv = tid >> 6;
  __shared__ __align__(16) float qlds[5][64];
  __shared__ float s_lds[5][2048];
  __shared__ float wredA[4], wredB[4];
  __shared__ int rows_s[5];
  __shared__ float part[4][5][64];
  for (int qq = tid; qq < 320; qq += 256) {
    int q = qq >> 6, d = qq & 63;
    int row = mtop[(b * 8 + h) * u + qb * 5 + q];
    if (d == 0) rows_s[q] = row;
    qlds[q][d] = Q[((size_t)b * Lc + row) * DMODEL + h * DKH + d];
  }
  __syncthreads();
  for (int k = tid; k < Lc; k += 256) {
    const float4* kp = reinterpret_cast<const float4*>(&Km[((size_t)b * Lc + k) * DMODEL + h * DKH]);
    float s0 = 0, s1 = 0, s2 = 0, s3 = 0, s4 = 0;
#pragma unroll
    for (int d = 0; d < 16; d++) {
      float4 kv = kp[d];
      float4 q0 = ((const float4*)qlds[0])[d];
      float4 q1 = ((const float4*)qlds[1])[d];
      float4 q2 = ((const float4*)qlds[2])[d];
      float4 q3 = ((const float4*)qlds[3])[d];
      float4 q4 = ((const float4*)qlds[4])[d];
      s0 += q0.x * kv.x + q0.y * kv.y + q0.z * kv.z + q0.w * kv.w;
      s1 += q1.x * kv.x + q1.y * kv.y + q1.z * kv.z + q1.w * kv.w;
      s2 += q2.x * kv.x + q2.y * kv.y + q2.z * kv.z + q2.w * kv.w;
      s3 += q3.x * kv.x + q3.y * kv.y + q3.z * kv.z + q3.w * kv.w;
      s4 += q4.x * kv.x + q4.y * kv.y + q4.z * kv.z + q4.w * kv.w;
    }
    s_lds[0][k] = s0 * 0.125f;
    s_lds[1][k] = s1 * 0.125f;
    s_lds[2][k] = s2 * 0.125f;
    s_lds[3][k] = s3 * 0.125f;
    s_lds[4][k] = s4 * 0.125f;
  }
  __syncthreads();
  float denomv[5];
#pragma unroll
  for (int q = 0; q < 5; q++) {
    float mx = -INFINITY;
    for (int k = tid; k < Lc; k += 256) mx = fmaxf(mx, s_lds[q][k]);
#pragma unroll
    for (int o = 32; o > 0; o >>= 1) mx = fmaxf(mx, __shfl_xor(mx, o));
    if (lane == 0) wredA[wv] = mx;
    __syncthreads();
    mx = fmaxf(fmaxf(wredA[0], wredA[1]), fmaxf(wredA[2], wredA[3]));
    float ls = 0.f;
    for (int k = tid; k < Lc; k += 256) {
      float w = expf(s_lds[q][k] - mx);
      s_lds[q][k] = w;
      ls += w;
    }
#pragma unroll
    for (int o = 32; o > 0; o >>= 1) ls += __shfl_xor(ls, o);
    if (lane == 0) wredB[wv] = ls;
    __syncthreads();
    denomv[q] = (wredB[0] + wredB[1]) + (wredB[2] + wredB[3]);
  }
  float acc0 = 0, acc1 = 0, acc2 = 0, acc3 = 0, acc4 = 0;
  int chunk = Lc >> 2;
  for (int k = wv * chunk; k < (wv + 1) * chunk; k++) {
    float vvv = V[((size_t)b * Lc + k) * DMODEL + h * DKH + lane];
    acc0 = fmaf(s_lds[0][k], vvv, acc0);
    acc1 = fmaf(s_lds[1][k], vvv, acc1);
    acc2 = fmaf(s_lds[2][k], vvv, acc2);
    acc3 = fmaf(s_lds[3][k], vvv, acc3);
    acc4 = fmaf(s_lds[4][k], vvv, acc4);
  }
  part[wv][0][lane] = acc0;
  part[wv][1][lane] = acc1;
  part[wv][2][lane] = acc2;
  part[wv][3][lane] = acc3;
  part[wv][4][lane] = acc4;
  __syncthreads();
  for (int q = wv; q < 5; q += 4) {
    float tot = ((part[0][q][lane] + part[1][q][lane]) +
                 (part[2][q][lane] + part[3][q][lane])) / denomv[q];
    size_t o = ((size_t)b * Lc + rows_s[q]) * DMODEL + h * DKH + lane;
    ctxh[o] = f2h(tot);
  }
}

// ---------------- y = LayerNorm(x+a)*g+b ; fp32 opt + fp16 out -------------
__global__ void k_add_ln(const float* __restrict__ x, const float* __restrict__ a,
                         const float* __restrict__ g, const float* __restrict__ be,
                         float* __restrict__ y, u16* __restrict__ yh) {
  int row = blockIdx.x;
  int tid = threadIdx.x;
  __shared__ float red[256];
  float2 xv = reinterpret_cast<const float2*>(x)[(size_t)row * 256 + tid];
  float2 av = reinterpret_cast<const float2*>(a)[(size_t)row * 256 + tid];
  float vx = xv.x + av.x, vy = xv.y + av.y;
  red[tid] = vx + vy;
  __syncthreads();
  for (int s = 128; s > 0; s >>= 1) {
    if (tid < s) red[tid] += red[tid + s];
    __syncthreads();
  }
  float mean = red[0] * (1.0f / 512.0f);
  __syncthreads();
  float dx = vx - mean, dy = vy - mean;
  red[tid] = dx * dx + dy * dy;
  __syncthreads();
  for (int s = 128; s > 0; s >>= 1) {
    if (tid < s) red[tid] += red[tid + s];
    __syncthreads();
  }
  float rstd = rsqrtf(red[0] * (1.0f / 512.0f) + 1e-5f);
  int c = tid * 2;
  float ox = dx * rstd * g[c] + be[c];
  float oy = dy * rstd * g[c + 1] + be[c + 1];
  if (y) {
    float2 o = {ox, oy};
    reinterpret_cast<float2*>(y)[(size_t)row * 256 + tid] = o;
  }
  if (yh) {
    size_t base = (size_t)row * 512 + c;
    yh[base] = f2h(ox);
    yh[base + 1] = f2h(oy);
  }
}

// ---------------- maxpool k=3 s=2, fp32 + fp16 out -------------------------
__global__ void k_pool(const float* __restrict__ cv, float* __restrict__ out,
                       u16* __restrict__ oh) {
  int g = blockIdx.x * 256 + threadIdx.x;
  int total = BATCH * LL2 * DMODEL;
  if (g >= total) return;
  int c = g & 511;
  int rest = g >> 9;
  int i = rest & (LL2 - 1);
  int b = rest >> 10;
  int t0 = 2 * i - 1;
  float m = -INFINITY;
#pragma unroll
  for (int k = 0; k < 3; k++) {
    int t = t0 + k;
    if (t >= 0 && t < LL1) m = fmaxf(m, cv[((size_t)b * LL1 + t) * DMODEL + c]);
  }
  out[g] = m;
  oh[g] = f2h(m);
}

// ---------------- gx = enc @ wih^T + bih (+ zero lstm tag buffer) ----------
__global__ void k_gx(const float* __restrict__ enc, const float* __restrict__ wih,
                     const float* __restrict__ bih, float* __restrict__ gx,
                     u64* __restrict__ hgl) {
  int g = blockIdx.x * 256 + threadIdx.x;
  if (g < 8192) hgl[g] = 0ull;
  if (g >= BATCH * 2048) return;
  int b = g >> 11, j = g & 2047;
  const float4* wp = reinterpret_cast<const float4*>(&wih[(size_t)j * 512]);
  const float4* ep = reinterpret_cast<const float4*>(&enc[b * 512]);
  float s = bih[j];
  for (int d = 0; d < 128; d++) {
    float4 w = wp[d], e = ep[d];
    s += w.x * e.x + w.y * e.y + w.z * e.z + w.w * e.w;
  }
  gx[g] = s;
}

// ---------------- persistent LSTM v5: tagged-u64 single-RT exchange --------
__global__ __launch_bounds__(256, 1) void k_lstm5(
    const float* __restrict__ gx, const float* __restrict__ whh,
    const float* __restrict__ bhh, const float* __restrict__ ow,
    const float* __restrict__ ob, float* __restrict__ out,
    u64* __restrict__ hglob) {
  const int bl = blockIdx.x, tid = threadIdx.x;
  const int part = tid >> 5, idx = tid & 31;
  const int gtype = idx >> 3, ml = idx & 7;
  const int j = gtype * 512 + bl * 8 + ml;
  __shared__ float h_s[4096];
  __shared__ float red[8][8][32];
  __shared__ float gvs[8][32];
  __shared__ float ow_s[512];
  __shared__ float ored[4];
  float w[64];
  {
    const float* wr = &whh[(size_t)j * 512 + part * 64];
#pragma unroll
    for (int r = 0; r < 64; r += 4) {
      float4 v = *(const float4*)&wr[r];
      w[r] = v.x; w[r + 1] = v.y; w[r + 2] = v.z; w[r + 3] = v.w;
    }
  }
  const float gxrow = gx[part * 2048 + j] + bhh[j];
  float cst = 0.f;
  for (int i = tid; i < 4096; i += 256) h_s[i] = 0.f;
  for (int i = tid; i < 512; i += 256) ow_s[i] = ow[i];
  const float obv = ob[0];
  __syncthreads();
  for (int t = 0; t < TPRED; t++) {
    float p[8];
#pragma unroll
    for (int b = 0; b < 8; b++) p[b] = 0.f;
#pragma unroll
    for (int r = 0; r < 64; r += 4) {
      float w0 = w[r], w1 = w[r + 1], w2 = w[r + 2], w3 = w[r + 3];
#pragma unroll
      for (int b = 0; b < 8; b++) {
        float4 hv = *(const float4*)&h_s[b * 512 + part * 64 + r];
        p[b] = fmaf(w3, hv.w, fmaf(w2, hv.z, fmaf(w1, hv.y, fmaf(w0, hv.x, p[b]))));
      }
    }
#pragma unroll
    for (int b = 0; b < 8; b++) red[b][part][idx] = p[b];
    __syncthreads();
    float gv = gxrow;
#pragma unroll
    for (int pp = 0; pp < 8; pp++) gv += red[part][pp][idx];
    gvs[part][idx] = gv;
    __syncthreads();
    u64* hgb = hglob + ((t + 1) & 1) * 4096;
    const u32 want = (u32)(t + 1);
    if (tid < 64) {
      int b = tid >> 3, m = tid & 7;
      float gi = gvs[b][m], gf = gvs[b][8 + m];
      float gg = gvs[b][16 + m], go = gvs[b][24 + m];
      float c = sigm(gf) * cst + sigm(gi) * tanhf(gg);
      cst = c;
      float hn = sigm(go) * tanhf(c);
      u64 word = ((u64)want << 32) | (u64)__builtin_bit_cast(u32, hn);
      __hip_atomic_store(&hgb[b * 512 + bl * 8 + m], word, __ATOMIC_RELAXED,
                         __HIP_MEMORY_SCOPE_AGENT);
    }
    {
      u64 v[16];
#pragma unroll
      for (int q = 0; q < 16; q++)
        v[q] = __hip_atomic_load(&hgb[q * 256 + tid], __ATOMIC_RELAXED,
                                 __HIP_MEMORY_SCOPE_AGENT);
      bool ok;
      do {
        ok = true;
#pragma unroll
        for (int q = 0; q < 16; q++) {
          if ((u32)(v[q] >> 32) != want) {
            ok = false;
            v[q] = __hip_atomic_load(&hgb[q * 256 + tid], __ATOMIC_RELAXED,
                                     __HIP_MEMORY_SCOPE_AGENT);
          }
        }
      } while (!ok);
#pragma unroll
      for (int q = 0; q < 16; q++)
        h_s[q * 256 + tid] = __builtin_bit_cast(float, (u32)(v[q] & 0xFFFFFFFFull));
    }
    __syncthreads();
    if (bl < 8) {
      float s = h_s[bl * 512 + tid] * ow_s[tid] +
                h_s[bl * 512 + 256 + tid] * ow_s[256 + tid];
#pragma unroll
      for (int o = 32; o > 0; o >>= 1) s += __shfl_xor(s, o);
      if ((tid & 63) == 0) ored[tid >> 6] = s;
      __syncthreads();
      if (tid == 0)
        out[bl * TPRED + t] = (ored[0] + ored[1]) + (ored[2] + ored[3]) + obv;
    }
  }
}

// ---------------------------------------------------------------------------
extern "C" void kernel_launch(void* const* d_in, const int* in_sizes, int n_in,
                              void* d_out, int out_size, void* d_ws, size_t ws_size,
                              hipStream_t stream) {
  const float* x = (const float*)d_in[0];
  const int* idx1 = (const int*)d_in[1];
  const int* idx2 = (const int*)d_in[2];
  const float* emb_w = (const float*)d_in[3];
  const float* emb_b = (const float*)d_in[4];
  const float* wq = (const float*)d_in[5];
  const float* bq = (const float*)d_in[6];
  const float* wk = (const float*)d_in[7];
  const float* bk = (const float*)d_in[8];
  const float* wv = (const float*)d_in[9];
  const float* bv = (const float*)d_in[10];
  const float* wo = (const float*)d_in[11];
  const float* bo = (const float*)d_in[12];
  const float* w1 = (const float*)d_in[13];
  const float* b1 = (const float*)d_in[14];
  const float* w2 = (const float*)d_in[15];
  const float* b2 = (const float*)d_in[16];
  const float* ln1g = (const float*)d_in[17];
  const float* ln1b = (const float*)d_in[18];
  const float* ln2g = (const float*)d_in[19];
  const float* ln2b = (const float*)d_in[20];
  const float* conv_w = (const float*)d_in[21];
  const float* conv_b = (const float*)d_in[22];
  const float* bn_g = (const float*)d_in[23];
  const float* bn_b = (const float*)d_in[24];
  const float* bn_m = (const float*)d_in[25];
  const float* bn_v = (const float*)d_in[26];
  const float* lstm_wih = (const float*)d_in[27];
  const float* lstm_whh = (const float*)d_in[28];
  const float* lstm_bih = (const float*)d_in[29];
  const float* lstm_bhh = (const float*)d_in[30];
  const float* out_w = (const float*)d_in[31];
  const float* out_b = (const float*)d_in[32];
  float* outp = (float*)d_out;

  char* ws = (char*)d_ws;
  const size_t MB = 1 << 20;
  float* S0 = (float*)(ws);
  float* S1 = (float*)(ws + 32 * MB);
  float* S2 = (float*)(ws + 64 * MB);
  float* S3 = (float*)(ws + 96 * MB);
  u16* P0 = (u16*)(ws + 128 * MB);
  u16* P1 = (u16*)(ws + 144 * MB);
  u16* P2 = (u16*)(ws + 160 * MB);
  u16* P3 = (u16*)(ws + 176 * MB);
  u16* WATT = (u16*)(ws + 192 * MB);
  u16* W1T = (u16*)(ws + 200 * MB);
  u16* W2T = (u16*)(ws + 208 * MB);
  u16* CWT = (u16*)(ws + 216 * MB);
  char* SMB = ws + 220 * MB;
  float* Mbuf = (float*)(SMB);
  float* csp = (float*)(SMB + 512 * 1024);
  u16* vmh = (u16*)(SMB + 1040 * 1024);
  int* mtop = (int*)(SMB + 1056 * 1024);
  float* gxb = (float*)(SMB + 1088 * 1024);
  float* encb = (float*)(SMB + 1152 * 1024);
  u64* hglob = (u64*)(SMB + 1168 * 1024);

  auto wat = [&](int l, int m, int hl) {
    return WATT + ((size_t)(l * 8 + hl * 4 + m)) * 262144;
  };

  // fused weight split (single dispatch)
  {
    dim3 g(4096, 13);
    k_splitall<<<g, 256, 0, stream>>>(wq, wk, wv, wo, w1, w2, conv_w,
                                      WATT, W1T, W2T, CWT);
  }

  auto mg = [&](const u16* Ah, const u16* Bh, const u16* Bl,
                const float* bias, float* C, int M, int N, int K) {
    dim3 g(N / 128, M / 128);
    k_mgemm<0, 0, 0, 0><<<g, 256, 0, stream>>>(
        Ah, Bh, Bl, bias, nullptr, nullptr, C, nullptr, nullptr,
        nullptr, M, N, K, 0, nullptr, nullptr, nullptr, nullptr);
  };
  auto mg3 = [&](const u16* Ah, const u16* Bh, const u16* Bl,
                 const float* b0_, const float* b1_, const float* b2_,
                 float* C0_, float* C1_, float* C2_, int M) {
    dim3 g(12, M / 128);
    k_mgemm<0, 0, 0, 1><<<g, 256, 0, stream>>>(
        Ah, Bh, Bl, b0_, b1_, b2_, C0_, C1_, C2_,
        nullptr, M, 1536, 512, 0, nullptr, nullptr, nullptr, nullptr);
  };

  // ---------------- embed ----------------
  k_embed<<<(BATCH * LL1) / 8, 256, 0, stream>>>(x, emb_w, emb_b, S0, P0);

  // ---------------- encoder layer 1 (L=2048, u=40) ----------------
  {
    const int Lc = LL1, u = 40, M = BATCH * LL1;
    mg3(P0, wat(0, 0, 0), wat(0, 0, 1), bq, bk, bv, S1, S2, S3, M);
    k_qk_m<<<M, 320, 0, stream>>>(S1, S2, idx1, Mbuf, Lc, u);
    k_topk<<<64, 256, 0, stream>>>(Mbuf, mtop, Lc, u);
    k_colsum1<<<dim3(BATCH, 32), 512, 0, stream>>>(S3, csp, Lc, Lc / 32);
    k_colsum2<<<BATCH, 512, 0, stream>>>(csp, nullptr, vmh, 32, 1.f / Lc);
    k_ctx_fillb<<<(BATCH * Lc * 128) / 256, 256, 0, stream>>>(P2, vmh, Lc);
    k_attn_mq<<<64 * 8, 256, 0, stream>>>(S1, S2, S3, mtop, P2, Lc, u, 8);
    mg(P2, wat(0, 3, 0), wat(0, 3, 1), bo, S1, M, 512, 512);
    k_add_ln<<<M, 256, 0, stream>>>(S0, S1, ln1g, ln1b, S2, P0);
    // FFN single dispatches: hid fp16 spans S0+S1 (64MB)
    u16* hid16 = (u16*)S0;
    {
      dim3 g1(16, 128);
      k_mgemm<1, 0, 1, 0><<<g1, 256, 0, stream>>>(
          P0, W1T, W1T + 1048576, b1,
          nullptr, nullptr, nullptr, nullptr, nullptr,
          hid16, 16384, 2048, 512, 0, nullptr, nullptr, nullptr, nullptr);
      dim3 g2(4, 128);
      k_mgemm<0, 0, 0, 0><<<g2, 256, 0, stream>>>(
          hid16, W2T, W2T + 1048576, b2, nullptr, nullptr,
          S3, nullptr, nullptr, nullptr,
          16384, 512, 2048, 0, nullptr, nullptr, nullptr, nullptr);
    }
    k_add_ln<<<M, 256, 0, stream>>>(S2, S3, ln2g, ln2b, nullptr, P0);
  }

  // ---------------- conv distill ----------------
  {
    dim3 g(4, 128);
    k_mgemm<2, 1, 0, 0><<<g, 256, 0, stream>>>(
        P0, CWT, CWT + 786432, conv_b, nullptr, nullptr,
        S1, nullptr, nullptr, nullptr, 16384, 512, 1536,
        LL1, bn_m, bn_v, bn_g, bn_b);
    k_pool<<<(BATCH * LL2 * 512) / 256, 256, 0, stream>>>(S1, S2, P0);
  }

  // ---------------- encoder layer 2 (L=1024, u=35) ----------------
  {
    const int Lc = LL2, u = 35, M = BATCH * LL2;
    float* Qb = S1;
    float* Kb = S1 + 4194304;
    float* Vb = S3;
    float* AOb = S3 + 4194304;
    mg3(P0, wat(1, 0, 0), wat(1, 0, 1), bq + 512, bk + 512, bv + 512,
        Qb, Kb, Vb, M);
    k_qk_m<<<M, 320, 0, stream>>>(Qb, Kb, idx2, Mbuf, Lc, u);
    k_topk<<<64, 256, 0, stream>>>(Mbuf, mtop, Lc, u);
    k_colsum1<<<dim3(BATCH, 32), 512, 0, stream>>>(Vb, csp, Lc, Lc / 32);
    k_colsum2<<<BATCH, 512, 0, stream>>>(csp, nullptr, vmh, 32, 1.f / Lc);
    k_ctx_fillb<<<(BATCH * Lc * 128) / 256, 256, 0, stream>>>(P2, vmh, Lc);
    k_attn_mq<<<64 * 7, 256, 0, stream>>>(Qb, Kb, Vb, mtop, P2, Lc, u, 7);
    mg(P2, wat(1, 3, 0), wat(1, 3, 1), bo + 512, AOb, M, 512, 512);
    k_add_ln<<<M, 256, 0, stream>>>(S2, AOb, ln1g + 512, ln1b + 512, S0, P0);
    u16* hid16 = (u16*)S1;   // 32MB (Q/K consumed)
    {
      dim3 g1(16, 64);
      k_mgemm<1, 0, 1, 0><<<g1, 256, 0, stream>>>(
          P0, W1T + (size_t)2 * 1048576, W1T + (size_t)3 * 1048576,
          b1 + 2048, nullptr, nullptr, nullptr, nullptr, nullptr,
          hid16, 8192, 2048, 512, 0, nullptr, nullptr, nullptr, nullptr);
      dim3 g2(4, 64);
      k_mgemm<0, 0, 0, 0><<<g2, 256, 0, stream>>>(
          hid16, W2T + (size_t)2 * 1048576, W2T + (size_t)3 * 1048576,
          b2 + 512, nullptr, nullptr, S2, nullptr, nullptr, nullptr,
          8192, 512, 2048, 0, nullptr, nullptr, nullptr, nullptr);
    }
    k_add_ln<<<M, 256, 0, stream>>>(S0, S2, ln2g + 512, ln2b + 512, S3, nullptr);
  }

  // ---------------- mean -> LSTM -> output ----------------
  k_colsum1<<<dim3(BATCH, 32), 512, 0, stream>>>(S3, csp, LL2, LL2 / 32);
  k_colsum2<<<BATCH, 512, 0, stream>>>(csp, encb, nullptr, 32, 1.f / LL2);
  k_gx<<<(BATCH * 2048) / 256, 256, 0, stream>>>(encb, lstm_wih, lstm_bih, gxb, hglob);
  k_lstm5<<<64, 256, 0, stream>>>(gxb, lstm_whh, lstm_bhh, out_w, out_b, outp, hglob);
}

// Round 12
// 2178.830 us; speedup vs baseline: 1.1298x; 1.0753x over previous
//
#include <hip/hip_runtime.h>
#include <hip/hip_bf16.h>
#include <math.h>

static constexpr int BATCH = 8;
static constexpr int LL1 = 2048;
static constexpr int LL2 = 1024;
static constexpr int DMODEL = 512;
static constexpr int NHEADS = 8;
static constexpr int DKH = 64;
static constexpr int TPRED = 100;

typedef unsigned short u16;
typedef unsigned int u32;
typedef unsigned long long u64;
typedef __attribute__((ext_vector_type(8))) _Float16 half8;
typedef __attribute__((ext_vector_type(2))) _Float16 half2_t;
typedef __attribute__((ext_vector_type(4))) float f32x4;

__device__ __forceinline__ float sigm(float x) { return 1.0f / (1.0f + expf(-x)); }

__device__ __forceinline__ u16 f2h(float f) {
  _Float16 h = (_Float16)f;
  return __builtin_bit_cast(u16, h);
}
__device__ __forceinline__ float h2f(u16 h) {
  return (float)__builtin_bit_cast(_Float16, h);
}
__device__ __forceinline__ float fdot2(u32 a, u32 b, float c) {
  return __builtin_amdgcn_fdot2(__builtin_bit_cast(half2_t, a),
                                __builtin_bit_cast(half2_t, b), c, false);
}

#define GLD16(gsrc, ldst) __builtin_amdgcn_global_load_lds( \
    (const __attribute__((address_space(1))) u32*)(gsrc),   \
    (__attribute__((address_space(3))) u32*)(ldst), 16, 0, 0)

// ---------------- embedding + posenc, writes fp32 + fp16 -------------------
__global__ void k_embed(const float* __restrict__ x, const float* __restrict__ ew,
                        const float* __restrict__ eb, float* __restrict__ out,
                        u16* __restrict__ oh) {
  int r0 = blockIdx.x * 8;
  int tid = threadIdx.x;
  __shared__ float xr[8][64];
  for (int i = tid; i < 512; i += 256)
    xr[i >> 6][i & 63] = x[(size_t)r0 * 64 + i];
  __syncthreads();
  const float fac = -9.210340371976184f / 512.0f;
  int l0 = r0 & (LL1 - 1);
  for (int c = tid; c < DMODEL; c += 256) {
    float acc[8];
#pragma unroll
    for (int r = 0; r < 8; r++) acc[r] = eb[c];
    for (int i = 0; i < 64; i++) {
      float w = ew[i * DMODEL + c];
#pragma unroll
      for (int r = 0; r < 8; r++) acc[r] = fmaf(xr[r][i], w, acc[r]);
    }
    float divv = expf((float)(2 * (c >> 1)) * fac);
#pragma unroll
    for (int r = 0; r < 8; r++) {
      float ang = (float)(l0 + r) * divv;
      float v = acc[r] + ((c & 1) ? cosf(ang) : sinf(ang));
      size_t o = (size_t)(r0 + r) * DMODEL + c;
      out[o] = v;
      oh[o] = f2h(v);
    }
  }
}

// ---------------- MFMA GEMM, fp16 act x fp16-split weights -----------------
// C = A@(Wh + Wl/1024) + bias. 2-phase pipelined double-buffer staging.
// Split-K: gridDim.z==2 -> block z computes K-half; z=1 writes partial to C1
// with bias zeroed (consumer sums). MULTI: fused QKV; K/V also emitted fp16.
template <int EPI, int CONV, int OSINGLE, int MULTI>
__global__ __launch_bounds__(256) void k_mgemm(
    const u16* __restrict__ Ah,
    const u16* __restrict__ Bh, const u16* __restrict__ Bl,
    const float* __restrict__ bias, const float* __restrict__ bias1,
    const float* __restrict__ bias2,
    float* __restrict__ C, float* __restrict__ C1, float* __restrict__ C2,
    u16* __restrict__ Ch, u16* __restrict__ Kh16, u16* __restrict__ Vh16,
    int M, int N, int K, int Lc,
    const float* __restrict__ p_m, const float* __restrict__ p_v,
    const float* __restrict__ p_g, const float* __restrict__ p_b) {
  __shared__ __align__(16) u16 As[2][4096], Bs_h[2][4096], Bs_l[2][4096];
  const int tid = threadIdx.x;
  const int m0 = blockIdx.y * 128, n0 = blockIdx.x * 128;
  const int wid = tid >> 6, lane = tid & 63;
  const int wm = (wid & 1) * 64, wn = (wid >> 1) * 64;
  const int lr = lane >> 4, lc = lane & 15;
  const int kz = (gridDim.z == 2) ? (int)blockIdx.z : 0;
  const int kb = (gridDim.z == 2) ? kz * (K >> 1) : 0;
  const int ke = (gridDim.z == 2) ? kb + (K >> 1) : K;
  f32x4 acc[4][4], acc2[4][4];
  f32x4 zz = {0.f, 0.f, 0.f, 0.f};
#pragma unroll
  for (int i = 0; i < 4; i++)
#pragma unroll
    for (int j = 0; j < 4; j++) { acc[i][j] = zz; acc2[i][j] = zz; }

  auto stage = [&](int sb, int k0) {
#pragma unroll
    for (int pass = 0; pass < 2; pass++) {
      int c = tid + pass * 256;
      int mi = c >> 2, kc = (c & 3) * 8;
      size_t asrc;
      if (CONV) {
        int m = m0 + mi;
        int b = m >> 11, t = m & (LL1 - 1);
        int kblk = k0 >> 9;
        int srow = (b << 11) + ((t + kblk - 1 + LL1) & (LL1 - 1));
        asrc = (size_t)srow * 512 + (k0 - (kblk << 9)) + kc;
      } else {
        asrc = (size_t)(m0 + mi) * K + k0 + kc;
      }
      size_t bsrc = (size_t)(n0 + mi) * K + k0 + kc;
      u32 ldo = (u32)((wid * 64 + pass * 256) * 8);
      GLD16(Ah + asrc, &As[sb][ldo]);
      GLD16(Bh + bsrc, &Bs_h[sb][ldo]);
      GLD16(Bl + bsrc, &Bs_l[sb][ldo]);
    }
  };

  stage(0, kb);
  __syncthreads();
  int sb = 0;
  for (int k0 = kb; k0 < ke; k0 += 32) {
    if (k0 + 32 < ke) stage(sb ^ 1, k0 + 32);
    const u16* Ap = As[sb];
    const u16* Bhp = Bs_h[sb];
    const u16* Blp = Bs_l[sb];
    half8 av[4], bh[4], bl[4];
#pragma unroll
    for (int i = 0; i < 4; i++) {
      int ar = (wm + i * 16 + lc) * 32 + lr * 8;
      int br = (wn + i * 16 + lc) * 32 + lr * 8;
      av[i] = *(const half8*)&Ap[ar];
      bh[i] = *(const half8*)&Bhp[br];
      bl[i] = *(const half8*)&Blp[br];
    }
#pragma unroll
    for (int i = 0; i < 4; i++)
#pragma unroll
      for (int j = 0; j < 4; j++) {
        acc[i][j] = __builtin_amdgcn_mfma_f32_16x16x32_f16(av[i], bh[j], acc[i][j], 0, 0, 0);
        acc2[i][j] = __builtin_amdgcn_mfma_f32_16x16x32_f16(av[i], bl[j], acc2[i][j], 0, 0, 0);
      }
    __syncthreads();
    sb ^= 1;
  }
#pragma unroll
  for (int j = 0; j < 4; j++) {
    int col = n0 + wn + j * 16 + lc;
    const float* bp = bias;
    float* Cp = C;
    int cw = col, Nw = N, sel = 0;
    if (MULTI) {
      sel = col >> 9;
      bp = sel == 0 ? bias : (sel == 1 ? bias1 : bias2);
      Cp = sel == 0 ? C : (sel == 1 ? C1 : C2);
      cw = col & 511;
      Nw = 512;
    } else if (kz == 1) {
      Cp = C1;
    }
    float bs = (kz == 0) ? bp[cw] : 0.f;
    float bnA = 0.f, bnB = 0.f;
    if (EPI == 2) {
      bnA = rsqrtf(p_v[cw] + 1e-5f) * p_g[cw];
      bnB = p_b[cw] - p_m[cw] * bnA;
    }
#pragma unroll
    for (int i = 0; i < 4; i++) {
#pragma unroll
      for (int q = 0; q < 4; q++) {
        int row = m0 + wm + i * 16 + lr * 4 + q;
        float t = fmaf(acc2[i][j][q], 0.0009765625f, acc[i][j][q]) + bs;
        if (EPI == 1) t = 0.5f * t * (1.0f + erff(t * 0.7071067811865475f));
        if (EPI == 2) { t = t * bnA + bnB; t = t > 0.f ? t : expm1f(t); }
        size_t o = (size_t)row * Nw + cw;
        if (OSINGLE) {
          Ch[o] = f2h(t);
        } else {
          Cp[o] = t;
          if (MULTI) {
            if (sel == 1 && Kh16) Kh16[o] = f2h(t);
            if (sel == 2 && Vh16) Vh16[o] = f2h(t);
          }
        }
      }
    }
  }
}

// ---------------- fused weight split/transpose (fp16 hi + lo*1024) ---------
__global__ void k_splitall(const float* __restrict__ wq, const float* __restrict__ wk,
                           const float* __restrict__ wv, const float* __restrict__ wo,
                           const float* __restrict__ w1, const float* __restrict__ w2,
                           const float* __restrict__ cw,
                           u16* __restrict__ WATT, u16* __restrict__ W1T,
                           u16* __restrict__ W2T, u16* __restrict__ CWT) {
  int job = blockIdx.y;
  int g = blockIdx.x * 256 + threadIdx.x;
  float v;
  u16 *dh, *dl;
  if (job < 8) {
    if (g >= 262144) return;
    int l = job >> 2, mi = job & 3;
    const float* src = (mi == 0 ? wq : mi == 1 ? wk : mi == 2 ? wv : wo) + (size_t)l * 262144;
    int n = g >> 9, k = g & 511;
    v = src[(size_t)k * 512 + n];
    dh = WATT + (size_t)(l * 8 + mi) * 262144;
    dl = dh + 4 * 262144;
  } else if (job == 8 || job == 10) {
    if (g >= 1048576) return;
    int l = (job == 10);
    int n = g >> 9, k = g & 511;
    v = w1[(size_t)l * 1048576 + (size_t)k * 2048 + n];
    dh = W1T + (size_t)(l * 2) * 1048576;
    dl = dh + 1048576;
  } else if (job == 9 || job == 11) {
    if (g >= 1048576) return;
    int l = (job == 11);
    int n = g >> 11, k = g & 2047;
    v = w2[(size_t)l * 1048576 + (size_t)k * 512 + n];
    dh = W2T + (size_t)(l * 2) * 1048576;
    dl = dh + 1048576;
  } else {
    if (g >= 786432) return;
    int c = g / 1536, k = g - c * 1536;
    int kblk = k >> 9, ci = k & 511;
    v = cw[c * 1536 + ci * 3 + kblk];
    dh = CWT;
    dl = CWT + 786432;
  }
  float wh = (float)(_Float16)v;
  dh[g] = f2h(v);
  dl[g] = f2h((v - wh) * 1024.0f);
}

// ---------------- sampled qk -> sparsity measure M (fp32) ------------------
__global__ void k_qk_m(const float* __restrict__ Q, const float* __restrict__ Km,
                       const int* __restrict__ idx, float* __restrict__ Mout,
                       int Lc, int u) {
  int row = blockIdx.x;
  int b = row / Lc, l = row - b * Lc;
  int tid = threadIdx.x;
  int nt = blockDim.x;
  __shared__ __align__(16) float qlds[DMODEL];
  __shared__ int ilds[40];
  __shared__ float qk[320];
  for (int i = tid; i < DMODEL; i += nt) qlds[i] = Q[(size_t)row * DMODEL + i];
  for (int i = tid; i < u; i += nt) ilds[i] = idx[l * u + i];
  __syncthreads();
  int tot = NHEADS * u;
  if (tid < tot) {
    int j = tid >> 3, h = tid & 7;
    int key = ilds[j];
    const float4* kp = reinterpret_cast<const float4*>(&Km[((size_t)b * Lc + key) * DMODEL + h * DKH]);
    const float4* qp = reinterpret_cast<const float4*>(&qlds[h * DKH]);
    float s = 0.f;
#pragma unroll
    for (int d = 0; d < 16; d++) {
      float4 kv = kp[d], qv = qp[d];
      s += qv.x * kv.x + qv.y * kv.y + qv.z * kv.z + qv.w * kv.w;
    }
    qk[tid] = s;
  }
  __syncthreads();
  if (tid < NHEADS) {
    int h = tid;
    float mx = -INFINITY, sm = 0.f;
    for (int j = 0; j < u; j++) {
      float v = qk[(j << 3) + h];
      mx = fmaxf(mx, v);
      sm += v;
    }
    Mout[((size_t)b * NHEADS + h) * Lc + l] = mx - sm / (float)Lc;
  }
}

// ---------------- top-u: register-resident tournament ----------------------
__global__ void k_topk(const float* __restrict__ Mv, int* __restrict__ mtop,
                       int Lc, int u) {
  int bh = blockIdx.x;
  int tid = threadIdx.x;
  int lane = tid & 63, wv = tid >> 6;
  __shared__ u64 wred[4];
  const int nk = Lc >> 8;
  u64 kk[8];
#pragma unroll
  for (int e = 0; e < 8; e++) {
    u64 key = 0;
    if (e < nk) {
      int i = e * 256 + tid;
      u32 ub = __builtin_bit_cast(u32, Mv[(size_t)bh * Lc + i]);
      ub = (ub & 0x80000000u) ? ~ub : (ub | 0x80000000u);
      key = ((u64)ub << 32) | (u64)(0xFFFFFFFFu - (u32)i);
    }
    kk[e] = key;
  }
  u64 lm = kk[0];
#pragma unroll
  for (int e = 1; e < 8; e++) lm = lm > kk[e] ? lm : kk[e];
  for (int it = 0; it < u; it++) {
    u64 best = lm;
#pragma unroll
    for (int o = 32; o > 0; o >>= 1) {
      u64 other = __shfl_xor(best, o);
      best = best > other ? best : other;
    }
    if (lane == 0) wred[wv] = best;
    __syncthreads();
    u64 b01 = wred[0] > wred[1] ? wred[0] : wred[1];
    u64 b23 = wred[2] > wred[3] ? wred[2] : wred[3];
    u64 b0 = b01 > b23 ? b01 : b23;
    int bi = (int)(0xFFFFFFFFu - (u32)(b0 & 0xFFFFFFFFull));
    if (tid == 0) mtop[bh * u + it] = bi;
    int s = bi & 255, e = bi >> 8;
    if (tid == s) {
#pragma unroll
      for (int e2 = 0; e2 < 8; e2++)
        if (e2 == e) kk[e2] = 0;
      lm = kk[0];
#pragma unroll
      for (int e2 = 1; e2 < 8; e2++) lm = lm > kk[e2] ? lm : kk[e2];
    }
    __syncthreads();
  }
}

// ---------------- column-sum two-phase -------------------------------------
__global__ void k_colsum1(const float* __restrict__ src, float* __restrict__ part,
                          int Lc, int rp) {
  int b = blockIdx.x, ch = blockIdx.y, c = threadIdx.x;
  const float* p = src + ((size_t)b * Lc + (size_t)ch * rp) * 512 + c;
  float s = 0.f;
  for (int r = 0; r < rp; r++) s += p[(size_t)r * 512];
  part[((b << 5) + ch) * 512 + c] = s;
}
__global__ void k_colsum2(const float* __restrict__ part, float* __restrict__ of,
                          u16* __restrict__ oh, int nch, float scale) {
  int b = blockIdx.x, c = threadIdx.x;
  float s = 0.f;
  for (int i = 0; i < nch; i++) s += part[(b * nch + i) * 512 + c];
  s *= scale;
  if (of) of[b * 512 + c] = s;
  if (oh) oh[b * 512 + c] = f2h(s);
}

// ---------------- fill context (fp16) with V-mean --------------------------
__global__ void k_ctx_fillb(u16* __restrict__ ch, const u16* __restrict__ vh,
                            int Lc) {
  int g = blockIdx.x * 256 + threadIdx.x;
  int total = BATCH * Lc * 128;
  if (g >= total) return;
  int c4 = g & 127;
  int row = g >> 7;
  int b = row / Lc;
  ((ushort4*)ch)[g] = ((const ushort4*)vh)[b * 128 + c4];
}

// ---------------- attention: fp16 K/V + fdot2 QK, 5 queries/block ----------
__global__ __launch_bounds__(256) void k_attn_mq(
    const float* __restrict__ Q, const u16* __restrict__ KH,
    const u16* __restrict__ VH, const int* __restrict__ mtop,
    u16* __restrict__ ctxh, int Lc, int u, int nqb) {
  int blk = blockIdx.x;
  int bh = blk & 63;
  int qb = blk >> 6;
  int h = bh & 7, b = bh >> 3;
  int tid = threadIdx.x;
  int lane = tid & 63, wv = tid >> 6;
  __shared__ u32 qpk[5][32];
  __shared__ float s_lds[5][2048];
  __shared__ float wredA[4], wredB[4];
  __shared__ int rows_s[5];
  __shared__ float part[4][5][64];
  for (int qq = tid; qq < 160; qq += 256) {   // 5 q x 32 pairs
    int q = qq >> 5, dp = qq & 31;
    int row = mtop[(b * 8 + h) * u + qb * 5 + q];
    if (dp == 0) rows_s[q] = row;
    const float* qp = &Q[((size_t)b * Lc + row) * DMODEL + h * DKH + dp * 2];
    qpk[q][dp] = (u32)f2h(qp[0]) | ((u32)f2h(qp[1]) << 16);
  }
  __syncthreads();
  for (int k = tid; k < Lc; k += 256) {
    const u32* kp = (const u32*)&KH[((size_t)b * Lc + k) * DMODEL + h * DKH];
    float s0 = 0, s1 = 0, s2 = 0, s3 = 0, s4 = 0;
#pragma unroll
    for (int w = 0; w < 32; w++) {
      u32 kw = kp[w];
      s0 = fdot2(kw, qpk[0][w], s0);
      s1 = fdot2(kw, qpk[1][w], s1);
      s2 = fdot2(kw, qpk[2][w], s2);
      s3 = fdot2(kw, qpk[3][w], s3);
      s4 = fdot2(kw, qpk[4][w], s4);
    }
    s_lds[0][k] = s0 * 0.125f;
    s_lds[1][k] = s1 * 0.125f;
    s_lds[2][k] = s2 * 0.125f;
    s_lds[3][k] = s3 * 0.125f;
    s_lds[4][k] = s4 * 0.125f;
  }
  __syncthreads();
  float denomv[5];
#pragma unroll
  for (int q = 0; q < 5; q++) {
    float mx = -INFINITY;
    for (int k = tid; k < Lc; k += 256) mx = fmaxf(mx, s_lds[q][k]);
#pragma unroll
    for (int o = 32; o > 0; o >>= 1) mx = fmaxf(mx, __shfl_xor(mx, o));
    if (lane == 0) wredA[wv] = mx;
    __syncthreads();
    mx = fmaxf(fmaxf(wredA[0], wredA[1]), fmaxf(wredA[2], wredA[3]));
    float ls = 0.f;
    for (int k = tid; k < Lc; k += 256) {
      float w = expf(s_lds[q][k] - mx);
      s_lds[q][k] = w;
      ls += w;
    }
#pragma unroll
    for (int o = 32; o > 0; o >>= 1) ls += __shfl_xor(ls, o);
    if (lane == 0) wredB[wv] = ls;
    __syncthreads();
    denomv[q] = (wredB[0] + wredB[1]) + (wredB[2] + wredB[3]);
  }
  float acc0 = 0, acc1 = 0, acc2 = 0, acc3 = 0, acc4 = 0;
  int chunk = Lc >> 2;
  for (int k = wv * chunk; k < (wv + 1) * chunk; k++) {
    float vvv = h2f(VH[((size_t)b * Lc + k) * DMODEL + h * DKH + lane]);
    acc0 = fmaf(s_lds[0][k], vvv, acc0);
    acc1 = fmaf(s_lds[1][k], vvv, acc1);
    acc2 = fmaf(s_lds[2][k], vvv, acc2);
    acc3 = fmaf(s_lds[3][k], vvv, acc3);
    acc4 = fmaf(s_lds[4][k], vvv, acc4);
  }
  part[wv][0][lane] = acc0;
  part[wv][1][lane] = acc1;
  part[wv][2][lane] = acc2;
  part[wv][3][lane] = acc3;
  part[wv][4][lane] = acc4;
  __syncthreads();
  for (int q = wv; q < 5; q += 4) {
    float tot = ((part[0][q][lane] + part[1][q][lane]) +
                 (part[2][q][lane] + part[3][q][lane])) / denomv[q];
    size_t o = ((size_t)b * Lc + rows_s[q]) * DMODEL + h * DKH + lane;
    ctxh[o] = f2h(tot);
  }
}

// ---------------- y = LayerNorm(x + a [+ a2])*g+b --------------------------
__global__ void k_add_ln(const float* __restrict__ x, const float* __restrict__ a,
                         const float* __restrict__ a2,
                         const float* __restrict__ g, const float* __restrict__ be,
                         float* __restrict__ y, u16* __restrict__ yh) {
  int row = blockIdx.x;
  int tid = threadIdx.x;
  __shared__ float red[256];
  float2 xv = reinterpret_cast<const float2*>(x)[(size_t)row * 256 + tid];
  float2 av = reinterpret_cast<const float2*>(a)[(size_t)row * 256 + tid];
  float vx = xv.x + av.x, vy = xv.y + av.y;
  if (a2) {
    float2 a2v = reinterpret_cast<const float2*>(a2)[(size_t)row * 256 + tid];
    vx += a2v.x;
    vy += a2v.y;
  }
  red[tid] = vx + vy;
  __syncthreads();
  for (int s = 128; s > 0; s >>= 1) {
    if (tid < s) red[tid] += red[tid + s];
    __syncthreads();
  }
  float mean = red[0] * (1.0f / 512.0f);
  __syncthreads();
  float dx = vx - mean, dy = vy - mean;
  red[tid] = dx * dx + dy * dy;
  __syncthreads();
  for (int s = 128; s > 0; s >>= 1) {
    if (tid < s) red[tid] += red[tid + s];
    __syncthreads();
  }
  float rstd = rsqrtf(red[0] * (1.0f / 512.0f) + 1e-5f);
  int c = tid * 2;
  float ox = dx * rstd * g[c] + be[c];
  float oy = dy * rstd * g[c + 1] + be[c + 1];
  if (y) {
    float2 o = {ox, oy};
    reinterpret_cast<float2*>(y)[(size_t)row * 256 + tid] = o;
  }
  if (yh) {
    size_t base = (size_t)row * 512 + c;
    yh[base] = f2h(ox);
    yh[base + 1] = f2h(oy);
  }
}

// ---------------- maxpool of elu(bn(p1+p2)), k=3 s=2 -----------------------
__global__ void k_pool(const float* __restrict__ cv1, const float* __restrict__ cv2,
                       const float* __restrict__ m_, const float* __restrict__ v_,
                       const float* __restrict__ g_, const float* __restrict__ b_,
                       float* __restrict__ out, u16* __restrict__ oh) {
  int g = blockIdx.x * 256 + threadIdx.x;
  int total = BATCH * LL2 * DMODEL;
  if (g >= total) return;
  int c = g & 511;
  int rest = g >> 9;
  int i = rest & (LL2 - 1);
  int b = rest >> 10;
  float bnA = rsqrtf(v_[c] + 1e-5f) * g_[c];
  float bnB = b_[c] - m_[c] * bnA;
  int t0 = 2 * i - 1;
  float mx = -INFINITY;
#pragma unroll
  for (int k = 0; k < 3; k++) {
    int t = t0 + k;
    if (t >= 0 && t < LL1) {
      size_t o = ((size_t)b * LL1 + t) * DMODEL + c;
      float y = (cv1[o] + cv2[o]) * bnA + bnB;
      y = y > 0.f ? y : expm1f(y);
      mx = fmaxf(mx, y);
    }
  }
  out[g] = mx;
  oh[g] = f2h(mx);
}

// ---------------- gx = enc @ wih^T + bih (+ zero lstm tag buffer) ----------
__global__ void k_gx(const float* __restrict__ enc, const float* __restrict__ wih,
                     const float* __restrict__ bih, float* __restrict__ gx,
                     u64* __restrict__ hgl) {
  int g = blockIdx.x * 256 + threadIdx.x;
  if (g < 8192) hgl[g] = 0ull;
  if (g >= BATCH * 2048) return;
  int b = g >> 11, j = g & 2047;
  const float4* wp = reinterpret_cast<const float4*>(&wih[(size_t)j * 512]);
  const float4* ep = reinterpret_cast<const float4*>(&enc[b * 512]);
  float s = bih[j];
  for (int d = 0; d < 128; d++) {
    float4 w = wp[d], e = ep[d];
    s += w.x * e.x + w.y * e.y + w.z * e.z + w.w * e.w;
  }
  gx[g] = s;
}

// ---------------- persistent LSTM v5: tagged-u64 single-RT exchange --------
__global__ __launch_bounds__(256, 1) void k_lstm5(
    const float* __restrict__ gx, const float* __restrict__ whh,
    const float* __restrict__ bhh, const float* __restrict__ ow,
    const float* __restrict__ ob, float* __restrict__ out,
    u64* __restrict__ hglob) {
  const int bl = blockIdx.x, tid = threadIdx.x;
  const int part = tid >> 5, idx = tid & 31;
  const int gtype = idx >> 3, ml = idx & 7;
  const int j = gtype * 512 + bl * 8 + ml;
  __shared__ float h_s[4096];
  __shared__ float red[8][8][32];
  __shared__ float gvs[8][32];
  __shared__ float ow_s[512];
  __shared__ float ored[4];
  float w[64];
  {
    const float* wr = &whh[(size_t)j * 512 + part * 64];
#pragma unroll
    for (int r = 0; r < 64; r += 4) {
      float4 v = *(const float4*)&wr[r];
      w[r] = v.x; w[r + 1] = v.y; w[r + 2] = v.z; w[r + 3] = v.w;
    }
  }
  const float gxrow = gx[part * 2048 + j] + bhh[j];
  float cst = 0.f;
  for (int i = tid; i < 4096; i += 256) h_s[i] = 0.f;
  for (int i = tid; i < 512; i += 256) ow_s[i] = ow[i];
  const float obv = ob[0];
  __syncthreads();
  for (int t = 0; t < TPRED; t++) {
    float p[8];
#pragma unroll
    for (int b = 0; b < 8; b++) p[b] = 0.f;
#pragma unroll
    for (int r = 0; r < 64; r += 4) {
      float w0 = w[r], w1 = w[r + 1], w2 = w[r + 2], w3 = w[r + 3];
#pragma unroll
      for (int b = 0; b < 8; b++) {
        float4 hv = *(const float4*)&h_s[b * 512 + part * 64 + r];
        p[b] = fmaf(w3, hv.w, fmaf(w2, hv.z, fmaf(w1, hv.y, fmaf(w0, hv.x, p[b]))));
      }
    }
#pragma unroll
    for (int b = 0; b < 8; b++) red[b][part][idx] = p[b];
    __syncthreads();
    float gv = gxrow;
#pragma unroll
    for (int pp = 0; pp < 8; pp++) gv += red[part][pp][idx];
    gvs[part][idx] = gv;
    __syncthreads();
    u64* hgb = hglob + ((t + 1) & 1) * 4096;
    const u32 want = (u32)(t + 1);
    if (tid < 64) {
      int b = tid >> 3, m = tid & 7;
      float gi = gvs[b][m], gf = gvs[b][8 + m];
      float gg = gvs[b][16 + m], go = gvs[b][24 + m];
      float c = sigm(gf) * cst + sigm(gi) * tanhf(gg);
      cst = c;
      float hn = sigm(go) * tanhf(c);
      u64 word = ((u64)want << 32) | (u64)__builtin_bit_cast(u32, hn);
      __hip_atomic_store(&hgb[b * 512 + bl * 8 + m], word, __ATOMIC_RELAXED,
                         __HIP_MEMORY_SCOPE_AGENT);
    }
    {
      u64 v[16];
#pragma unroll
      for (int q = 0; q < 16; q++)
        v[q] = __hip_atomic_load(&hgb[q * 256 + tid], __ATOMIC_RELAXED,
                                 __HIP_MEMORY_SCOPE_AGENT);
      bool ok;
      do {
        ok = true;
#pragma unroll
        for (int q = 0; q < 16; q++) {
          if ((u32)(v[q] >> 32) != want) {
            ok = false;
            v[q] = __hip_atomic_load(&hgb[q * 256 + tid], __ATOMIC_RELAXED,
                                     __HIP_MEMORY_SCOPE_AGENT);
          }
        }
      } while (!ok);
#pragma unroll
      for (int q = 0; q < 16; q++)
        h_s[q * 256 + tid] = __builtin_bit_cast(float, (u32)(v[q] & 0xFFFFFFFFull));
    }
    __syncthreads();
    if (bl < 8) {
      float s = h_s[bl * 512 + tid] * ow_s[tid] +
                h_s[bl * 512 + 256 + tid] * ow_s[256 + tid];
#pragma unroll
      for (int o = 32; o > 0; o >>= 1) s += __shfl_xor(s, o);
      if ((tid & 63) == 0) ored[tid >> 6] = s;
      __syncthreads();
      if (tid == 0)
        out[bl * TPRED + t] = (ored[0] + ored[1]) + (ored[2] + ored[3]) + obv;
    }
  }
}

// ---------------------------------------------------------------------------
extern "C" void kernel_launch(void* const* d_in, const int* in_sizes, int n_in,
                              void* d_out, int out_size, void* d_ws, size_t ws_size,
                              hipStream_t stream) {
  const float* x = (const float*)d_in[0];
  const int* idx1 = (const int*)d_in[1];
  const int* idx2 = (const int*)d_in[2];
  const float* emb_w = (const float*)d_in[3];
  const float* emb_b = (const float*)d_in[4];
  const float* wq = (const float*)d_in[5];
  const float* bq = (const float*)d_in[6];
  const float* wk = (const float*)d_in[7];
  const float* bk = (const float*)d_in[8];
  const float* wv = (const float*)d_in[9];
  const float* bv = (const float*)d_in[10];
  const float* wo = (const float*)d_in[11];
  const float* bo = (const float*)d_in[12];
  const float* w1 = (const float*)d_in[13];
  const float* b1 = (const float*)d_in[14];
  const float* w2 = (const float*)d_in[15];
  const float* b2 = (const float*)d_in[16];
  const float* ln1g = (const float*)d_in[17];
  const float* ln1b = (const float*)d_in[18];
  const float* ln2g = (const float*)d_in[19];
  const float* ln2b = (const float*)d_in[20];
  const float* conv_w = (const float*)d_in[21];
  const float* conv_b = (const float*)d_in[22];
  const float* bn_g = (const float*)d_in[23];
  const float* bn_b = (const float*)d_in[24];
  const float* bn_m = (const float*)d_in[25];
  const float* bn_v = (const float*)d_in[26];
  const float* lstm_wih = (const float*)d_in[27];
  const float* lstm_whh = (const float*)d_in[28];
  const float* lstm_bih = (const float*)d_in[29];
  const float* lstm_bhh = (const float*)d_in[30];
  const float* out_w = (const float*)d_in[31];
  const float* out_b = (const float*)d_in[32];
  float* outp = (float*)d_out;

  char* ws = (char*)d_ws;
  const size_t MB = 1 << 20;
  float* S0 = (float*)(ws);
  float* S1 = (float*)(ws + 32 * MB);
  float* S2 = (float*)(ws + 64 * MB);
  float* S3 = (float*)(ws + 96 * MB);
  u16* P0 = (u16*)(ws + 128 * MB);
  u16* P1 = (u16*)(ws + 144 * MB);
  u16* P2 = (u16*)(ws + 160 * MB);
  u16* P3 = (u16*)(ws + 176 * MB);
  float* PP = (float*)(ws + 160 * MB);     // 32MB fp32 alias of P2+P3
  u16* WATT = (u16*)(ws + 192 * MB);
  u16* W1T = (u16*)(ws + 200 * MB);
  u16* W2T = (u16*)(ws + 208 * MB);
  u16* CWT = (u16*)(ws + 216 * MB);
  char* SMB = ws + 220 * MB;
  float* Mbuf = (float*)(SMB);
  float* csp = (float*)(SMB + 512 * 1024);
  u16* vmh = (u16*)(SMB + 1040 * 1024);
  int* mtop = (int*)(SMB + 1056 * 1024);
  float* gxb = (float*)(SMB + 1088 * 1024);
  float* encb = (float*)(SMB + 1152 * 1024);
  u64* hglob = (u64*)(SMB + 1168 * 1024);

  auto wat = [&](int l, int m, int hl) {
    return WATT + ((size_t)(l * 8 + hl * 4 + m)) * 262144;
  };

  {
    dim3 g(4096, 13);
    k_splitall<<<g, 256, 0, stream>>>(wq, wk, wv, wo, w1, w2, conv_w,
                                      WATT, W1T, W2T, CWT);
  }

  // split-K x2 GEMM for N=512: p1 -> C, p2 -> C1 (consumer sums)
  auto mgsk = [&](const u16* Ah, const u16* Bh, const u16* Bl,
                  const float* bias, float* Cb, float* Cp2, int M, int K) {
    dim3 g(4, M / 128, 2);
    k_mgemm<0, 0, 0, 0><<<g, 256, 0, stream>>>(
        Ah, Bh, Bl, bias, nullptr, nullptr, Cb, Cp2, nullptr,
        nullptr, nullptr, nullptr, M, 512, K, 0,
        nullptr, nullptr, nullptr, nullptr);
  };
  auto mg3 = [&](const u16* Ah, const u16* Bh, const u16* Bl,
                 const float* b0_, const float* b1_, const float* b2_,
                 float* C0_, float* C1_, float* C2_, u16* KH, u16* VH, int M) {
    dim3 g(12, M / 128);
    k_mgemm<0, 0, 0, 1><<<g, 256, 0, stream>>>(
        Ah, Bh, Bl, b0_, b1_, b2_, C0_, C1_, C2_,
        nullptr, KH, VH, M, 1536, 512, 0, nullptr, nullptr, nullptr, nullptr);
  };

  // ---------------- embed ----------------
  k_embed<<<(BATCH * LL1) / 8, 256, 0, stream>>>(x, emb_w, emb_b, S0, P0);

  // ---------------- encoder layer 1 (L=2048, u=40) ----------------
  {
    const int Lc = LL1, u = 40, M = BATCH * LL1;
    mg3(P0, wat(0, 0, 0), wat(0, 0, 1), bq, bk, bv, S1, S2, S3, P1, P3, M);
    k_qk_m<<<M, 320, 0, stream>>>(S1, S2, idx1, Mbuf, Lc, u);
    k_topk<<<64, 256, 0, stream>>>(Mbuf, mtop, Lc, u);
    k_colsum1<<<dim3(BATCH, 32), 512, 0, stream>>>(S3, csp, Lc, Lc / 32);
    k_colsum2<<<BATCH, 512, 0, stream>>>(csp, nullptr, vmh, 32, 1.f / Lc);
    k_ctx_fillb<<<(BATCH * Lc * 128) / 256, 256, 0, stream>>>(P2, vmh, Lc);
    k_attn_mq<<<64 * 8, 256, 0, stream>>>(S1, P1, P3, mtop, P2, Lc, u, 8);
    // attn out-proj, split-K: p1 -> S1, p2 -> S3 (Q/V fp32 consumed)
    mgsk(P2, wat(0, 3, 0), wat(0, 3, 1), bo, S1, S3, M, 512);
    k_add_ln<<<M, 256, 0, stream>>>(S0, S1, S3, ln1g, ln1b, S2, P0);
    u16* hid16 = (u16*)S0;   // spans S0+S1 (64MB)
    {
      dim3 g1(16, 128);
      k_mgemm<1, 0, 1, 0><<<g1, 256, 0, stream>>>(
          P0, W1T, W1T + 1048576, b1, nullptr, nullptr,
          nullptr, nullptr, nullptr, hid16, nullptr, nullptr,
          16384, 2048, 512, 0, nullptr, nullptr, nullptr, nullptr);
    }
    // FFN2 split-K: p1 -> S3, p2 -> PP
    mgsk(hid16, W2T, W2T + 1048576, b2, S3, PP, M, 2048);
    k_add_ln<<<M, 256, 0, stream>>>(S2, S3, PP, ln2g, ln2b, nullptr, P0);
  }

  // ---------------- conv distill (split-K, BN+ELU in pool) ----------------
  {
    dim3 g(4, 128, 2);
    k_mgemm<0, 1, 0, 0><<<g, 256, 0, stream>>>(
        P0, CWT, CWT + 786432, conv_b, nullptr, nullptr,
        S0, S1, nullptr, nullptr, nullptr, nullptr, 16384, 512, 1536,
        LL1, nullptr, nullptr, nullptr, nullptr);
    k_pool<<<(BATCH * LL2 * 512) / 256, 256, 0, stream>>>(
        S0, S1, bn_m, bn_v, bn_g, bn_b, S2, P0);
  }

  // ---------------- encoder layer 2 (L=1024, u=35) ----------------
  {
    const int Lc = LL2, u = 35, M = BATCH * LL2;
    float* Qb = S1;
    float* Kb = S1 + 4194304;
    float* Vb = S3;
    mg3(P0, wat(1, 0, 0), wat(1, 0, 1), bq + 512, bk + 512, bv + 512,
        Qb, Kb, Vb, P1, P3, M);
    k_qk_m<<<M, 320, 0, stream>>>(Qb, Kb, idx2, Mbuf, Lc, u);
    k_topk<<<64, 256, 0, stream>>>(Mbuf, mtop, Lc, u);
    k_colsum1<<<dim3(BATCH, 32), 512, 0, stream>>>(Vb, csp, Lc, Lc / 32);
    k_colsum2<<<BATCH, 512, 0, stream>>>(csp, nullptr, vmh, 32, 1.f / Lc);
    k_ctx_fillb<<<(BATCH * Lc * 128) / 256, 256, 0, stream>>>(P2, vmh, Lc);
    k_attn_mq<<<64 * 7, 256, 0, stream>>>(Qb, P1, P3, mtop, P2, Lc, u, 7);
    // attn out-proj split-K: p1 -> S3, p2 -> S3+16MB
    mgsk(P2, wat(1, 3, 0), wat(1, 3, 1), bo + 512, S3, S3 + 4194304, M, 512);
    k_add_ln<<<M, 256, 0, stream>>>(S2, S3, S3 + 4194304,
                                    ln1g + 512, ln1b + 512, S0, P0);
    u16* hid16 = (u16*)S1;   // 32MB
    {
      dim3 g1(16, 64);
      k_mgemm<1, 0, 1, 0><<<g1, 256, 0, stream>>>(
          P0, W1T + (size_t)2 * 1048576, W1T + (size_t)3 * 1048576,
          b1 + 2048, nullptr, nullptr, nullptr, nullptr, nullptr,
          hid16, nullptr, nullptr, 8192, 2048, 512, 0,
          nullptr, nullptr, nullptr, nullptr);
    }
    // FFN2 split-K: p1 -> S2, p2 -> S2+16MB
    mgsk(hid16, W2T + (size_t)2 * 1048576, W2T + (size_t)3 * 1048576,
         b2 + 512, S2, S2 + 4194304, M, 2048);
    k_add_ln<<<M, 256, 0, stream>>>(S0, S2, S2 + 4194304,
                                    ln2g + 512, ln2b + 512, S3, nullptr);
  }

  // ---------------- mean -> LSTM -> output ----------------
  k_colsum1<<<dim3(BATCH, 32), 512, 0, stream>>>(S3, csp, LL2, LL2 / 32);
  k_colsum2<<<BATCH, 512, 0, stream>>>(csp, encb, nullptr, 32, 1.f / LL2);
  k_gx<<<(BATCH * 2048) / 256, 256, 0, stream>>>(encb, lstm_wih, lstm_bih, gxb, hglob);
  k_lstm5<<<64, 256, 0, stream>>>(gxb, lstm_whh, lstm_bhh, out_w, out_b, outp, hglob);
}

// Round 13
// 1885.649 us; speedup vs baseline: 1.3054x; 1.1555x over previous
//
#include <hip/hip_runtime.h>
#include <hip/hip_bf16.h>
#include <math.h>

static constexpr int BATCH = 8;
static constexpr int LL1 = 2048;
static constexpr int LL2 = 1024;
static constexpr int DMODEL = 512;
static constexpr int NHEADS = 8;
static constexpr int DKH = 64;
static constexpr int TPRED = 100;

typedef unsigned short u16;
typedef unsigned int u32;
typedef unsigned long long u64;
typedef __attribute__((ext_vector_type(8))) _Float16 half8;
typedef __attribute__((ext_vector_type(2))) _Float16 half2_t;
typedef __attribute__((ext_vector_type(4))) float f32x4;

__device__ __forceinline__ float sigm(float x) { return 1.0f / (1.0f + expf(-x)); }

__device__ __forceinline__ u16 f2h(float f) {
  _Float16 h = (_Float16)f;
  return __builtin_bit_cast(u16, h);
}
__device__ __forceinline__ float h2f(u16 h) {
  return (float)__builtin_bit_cast(_Float16, h);
}
__device__ __forceinline__ float fdot2(u32 a, u32 b, float c) {
  return __builtin_amdgcn_fdot2(__builtin_bit_cast(half2_t, a),
                                __builtin_bit_cast(half2_t, b), c, false);
}

#define GLD16(gsrc, ldst) __builtin_amdgcn_global_load_lds( \
    (const __attribute__((address_space(1))) u32*)(gsrc),   \
    (__attribute__((address_space(3))) u32*)(ldst), 16, 0, 0)

// ---------------- embedding + posenc, writes fp32 + fp16 -------------------
__global__ void k_embed(const float* __restrict__ x, const float* __restrict__ ew,
                        const float* __restrict__ eb, float* __restrict__ out,
                        u16* __restrict__ oh) {
  int r0 = blockIdx.x * 8;
  int tid = threadIdx.x;
  __shared__ float xr[8][64];
  for (int i = tid; i < 512; i += 256)
    xr[i >> 6][i & 63] = x[(size_t)r0 * 64 + i];
  __syncthreads();
  const float fac = -9.210340371976184f / 512.0f;
  int l0 = r0 & (LL1 - 1);
  for (int c = tid; c < DMODEL; c += 256) {
    float acc[8];
#pragma unroll
    for (int r = 0; r < 8; r++) acc[r] = eb[c];
    for (int i = 0; i < 64; i++) {
      float w = ew[i * DMODEL + c];
#pragma unroll
      for (int r = 0; r < 8; r++) acc[r] = fmaf(xr[r][i], w, acc[r]);
    }
    float divv = expf((float)(2 * (c >> 1)) * fac);
#pragma unroll
    for (int r = 0; r < 8; r++) {
      float ang = (float)(l0 + r) * divv;
      float v = acc[r] + ((c & 1) ? cosf(ang) : sinf(ang));
      size_t o = (size_t)(r0 + r) * DMODEL + c;
      out[o] = v;
      oh[o] = f2h(v);
    }
  }
}

// ---------------- MFMA GEMM, 512 thr, 128x256 tile -------------------------
// C = A@(Wh + Wl/1024) + bias. 8 waves (2 row x 4 col), BK=32, 2-phase
// pipelined double-buffer. Split-K via gridDim.z==2 (z=1 -> C1, bias 0).
// MULTI: fused QKV (N=1536) routed per 512-col block; K/V also fp16.
template <int EPI, int CONV, int OSINGLE, int MULTI>
__global__ __launch_bounds__(512, 2) void k_mgemm(
    const u16* __restrict__ Ah,
    const u16* __restrict__ Bh, const u16* __restrict__ Bl,
    const float* __restrict__ bias, const float* __restrict__ bias1,
    const float* __restrict__ bias2,
    float* __restrict__ C, float* __restrict__ C1, float* __restrict__ C2,
    u16* __restrict__ Ch, u16* __restrict__ Kh16, u16* __restrict__ Vh16,
    int M, int N, int K, int Lc,
    const float* __restrict__ p_m, const float* __restrict__ p_v,
    const float* __restrict__ p_g, const float* __restrict__ p_b) {
  __shared__ __align__(16) u16 As[2][4096], Bs_h[2][8192], Bs_l[2][8192];
  const int tid = threadIdx.x;
  const int m0 = blockIdx.y * 128, n0 = blockIdx.x * 256;
  const int wid = tid >> 6, lane = tid & 63;
  const int wm = (wid & 1) * 64, wn = (wid >> 1) * 64;
  const int lr = lane >> 4, lc = lane & 15;
  const int kz = (gridDim.z == 2) ? (int)blockIdx.z : 0;
  const int kb = (gridDim.z == 2) ? kz * (K >> 1) : 0;
  const int ke = (gridDim.z == 2) ? kb + (K >> 1) : K;
  f32x4 acc[4][4], acc2[4][4];
  f32x4 zz = {0.f, 0.f, 0.f, 0.f};
#pragma unroll
  for (int i = 0; i < 4; i++)
#pragma unroll
    for (int j = 0; j < 4; j++) { acc[i][j] = zz; acc2[i][j] = zz; }

  auto stage = [&](int sb, int k0) {
    // A: 512 GLD16 (one per thread)
    {
      int c = tid;
      int mi = c >> 2, kc = (c & 3) * 8;
      size_t asrc;
      if (CONV) {
        int m = m0 + mi;
        int b = m >> 11, t = m & (LL1 - 1);
        int kblk = k0 >> 9;
        int srow = (b << 11) + ((t + kblk - 1 + LL1) & (LL1 - 1));
        asrc = (size_t)srow * 512 + (k0 - (kblk << 9)) + kc;
      } else {
        asrc = (size_t)(m0 + mi) * K + k0 + kc;
      }
      GLD16(Ah + asrc, &As[sb][(u32)(c * 8)]);
    }
    // B: 1024 GLD16 each for Bh, Bl (2 passes)
#pragma unroll
    for (int pass = 0; pass < 2; pass++) {
      int c = tid + pass * 512;
      int mi = c >> 2, kc = (c & 3) * 8;
      size_t bsrc = (size_t)(n0 + mi) * K + k0 + kc;
      u32 ldo = (u32)(c * 8);
      GLD16(Bh + bsrc, &Bs_h[sb][ldo]);
      GLD16(Bl + bsrc, &Bs_l[sb][ldo]);
    }
  };

  stage(0, kb);
  __syncthreads();
  int sb = 0;
  for (int k0 = kb; k0 < ke; k0 += 32) {
    if (k0 + 32 < ke) stage(sb ^ 1, k0 + 32);
    const u16* Ap = As[sb];
    const u16* Bhp = Bs_h[sb];
    const u16* Blp = Bs_l[sb];
    half8 av[4], bh[4], bl[4];
#pragma unroll
    for (int i = 0; i < 4; i++) {
      int ar = (wm + i * 16 + lc) * 32 + lr * 8;
      int br = (wn + i * 16 + lc) * 32 + lr * 8;
      av[i] = *(const half8*)&Ap[ar];
      bh[i] = *(const half8*)&Bhp[br];
      bl[i] = *(const half8*)&Blp[br];
    }
#pragma unroll
    for (int i = 0; i < 4; i++)
#pragma unroll
      for (int j = 0; j < 4; j++) {
        acc[i][j] = __builtin_amdgcn_mfma_f32_16x16x32_f16(av[i], bh[j], acc[i][j], 0, 0, 0);
        acc2[i][j] = __builtin_amdgcn_mfma_f32_16x16x32_f16(av[i], bl[j], acc2[i][j], 0, 0, 0);
      }
    __syncthreads();
    sb ^= 1;
  }
#pragma unroll
  for (int j = 0; j < 4; j++) {
    int col = n0 + wn + j * 16 + lc;
    const float* bp = bias;
    float* Cp = C;
    int cw = col, Nw = N, sel = 0;
    if (MULTI) {
      sel = col >> 9;
      bp = sel == 0 ? bias : (sel == 1 ? bias1 : bias2);
      Cp = sel == 0 ? C : (sel == 1 ? C1 : C2);
      cw = col & 511;
      Nw = 512;
    } else if (kz == 1) {
      Cp = C1;
    }
    float bs = (kz == 0) ? bp[cw] : 0.f;
    float bnA = 0.f, bnB = 0.f;
    if (EPI == 2) {
      bnA = rsqrtf(p_v[cw] + 1e-5f) * p_g[cw];
      bnB = p_b[cw] - p_m[cw] * bnA;
    }
#pragma unroll
    for (int i = 0; i < 4; i++) {
#pragma unroll
      for (int q = 0; q < 4; q++) {
        int row = m0 + wm + i * 16 + lr * 4 + q;
        float t = fmaf(acc2[i][j][q], 0.0009765625f, acc[i][j][q]) + bs;
        if (EPI == 1) t = 0.5f * t * (1.0f + erff(t * 0.7071067811865475f));
        if (EPI == 2) { t = t * bnA + bnB; t = t > 0.f ? t : expm1f(t); }
        size_t o = (size_t)row * Nw + cw;
        if (OSINGLE) {
          Ch[o] = f2h(t);
        } else {
          Cp[o] = t;
          if (MULTI) {
            if (sel == 1 && Kh16) Kh16[o] = f2h(t);
            if (sel == 2 && Vh16) Vh16[o] = f2h(t);
          }
        }
      }
    }
  }
}

// ---------------- fused weight split/transpose (fp16 hi + lo*1024) ---------
__global__ void k_splitall(const float* __restrict__ wq, const float* __restrict__ wk,
                           const float* __restrict__ wv, const float* __restrict__ wo,
                           const float* __restrict__ w1, const float* __restrict__ w2,
                           const float* __restrict__ cw,
                           u16* __restrict__ WATT, u16* __restrict__ W1T,
                           u16* __restrict__ W2T, u16* __restrict__ CWT) {
  int job = blockIdx.y;
  int g = blockIdx.x * 256 + threadIdx.x;
  float v;
  u16 *dh, *dl;
  if (job < 8) {
    if (g >= 262144) return;
    int l = job >> 2, mi = job & 3;
    const float* src = (mi == 0 ? wq : mi == 1 ? wk : mi == 2 ? wv : wo) + (size_t)l * 262144;
    int n = g >> 9, k = g & 511;
    v = src[(size_t)k * 512 + n];
    dh = WATT + (size_t)(l * 8 + mi) * 262144;
    dl = dh + 4 * 262144;
  } else if (job == 8 || job == 10) {
    if (g >= 1048576) return;
    int l = (job == 10);
    int n = g >> 9, k = g & 511;
    v = w1[(size_t)l * 1048576 + (size_t)k * 2048 + n];
    dh = W1T + (size_t)(l * 2) * 1048576;
    dl = dh + 1048576;
  } else if (job == 9 || job == 11) {
    if (g >= 1048576) return;
    int l = (job == 11);
    int n = g >> 11, k = g & 2047;
    v = w2[(size_t)l * 1048576 + (size_t)k * 512 + n];
    dh = W2T + (size_t)(l * 2) * 1048576;
    dl = dh + 1048576;
  } else {
    if (g >= 786432) return;
    int c = g / 1536, k = g - c * 1536;
    int kblk = k >> 9, ci = k & 511;
    v = cw[c * 1536 + ci * 3 + kblk];
    dh = CWT;
    dl = CWT + 786432;
  }
  float wh = (float)(_Float16)v;
  dh[g] = f2h(v);
  dl[g] = f2h((v - wh) * 1024.0f);
}

// ---------------- sampled qk -> sparsity measure M (fp32) ------------------
__global__ void k_qk_m(const float* __restrict__ Q, const float* __restrict__ Km,
                       const int* __restrict__ idx, float* __restrict__ Mout,
                       int Lc, int u) {
  int row = blockIdx.x;
  int b = row / Lc, l = row - b * Lc;
  int tid = threadIdx.x;
  int nt = blockDim.x;
  __shared__ __align__(16) float qlds[DMODEL];
  __shared__ int ilds[40];
  __shared__ float qk[320];
  for (int i = tid; i < DMODEL; i += nt) qlds[i] = Q[(size_t)row * DMODEL + i];
  for (int i = tid; i < u; i += nt) ilds[i] = idx[l * u + i];
  __syncthreads();
  int tot = NHEADS * u;
  if (tid < tot) {
    int j = tid >> 3, h = tid & 7;
    int key = ilds[j];
    const float4* kp = reinterpret_cast<const float4*>(&Km[((size_t)b * Lc + key) * DMODEL + h * DKH]);
    const float4* qp = reinterpret_cast<const float4*>(&qlds[h * DKH]);
    float s = 0.f;
#pragma unroll
    for (int d = 0; d < 16; d++) {
      float4 kv = kp[d], qv = qp[d];
      s += qv.x * kv.x + qv.y * kv.y + qv.z * kv.z + qv.w * kv.w;
    }
    qk[tid] = s;
  }
  __syncthreads();
  if (tid < NHEADS) {
    int h = tid;
    float mx = -INFINITY, sm = 0.f;
    for (int j = 0; j < u; j++) {
      float v = qk[(j << 3) + h];
      mx = fmaxf(mx, v);
      sm += v;
    }
    Mout[((size_t)b * NHEADS + h) * Lc + l] = mx - sm / (float)Lc;
  }
}

// ---------------- top-u: register-resident tournament ----------------------
__global__ void k_topk(const float* __restrict__ Mv, int* __restrict__ mtop,
                       int Lc, int u) {
  int bh = blockIdx.x;
  int tid = threadIdx.x;
  int lane = tid & 63, wv = tid >> 6;
  __shared__ u64 wred[4];
  const int nk = Lc >> 8;
  u64 kk[8];
#pragma unroll
  for (int e = 0; e < 8; e++) {
    u64 key = 0;
    if (e < nk) {
      int i = e * 256 + tid;
      u32 ub = __builtin_bit_cast(u32, Mv[(size_t)bh * Lc + i]);
      ub = (ub & 0x80000000u) ? ~ub : (ub | 0x80000000u);
      key = ((u64)ub << 32) | (u64)(0xFFFFFFFFu - (u32)i);
    }
    kk[e] = key;
  }
  u64 lm = kk[0];
#pragma unroll
  for (int e = 1; e < 8; e++) lm = lm > kk[e] ? lm : kk[e];
  for (int it = 0; it < u; it++) {
    u64 best = lm;
#pragma unroll
    for (int o = 32; o > 0; o >>= 1) {
      u64 other = __shfl_xor(best, o);
      best = best > other ? best : other;
    }
    if (lane == 0) wred[wv] = best;
    __syncthreads();
    u64 b01 = wred[0] > wred[1] ? wred[0] : wred[1];
    u64 b23 = wred[2] > wred[3] ? wred[2] : wred[3];
    u64 b0 = b01 > b23 ? b01 : b23;
    int bi = (int)(0xFFFFFFFFu - (u32)(b0 & 0xFFFFFFFFull));
    if (tid == 0) mtop[bh * u + it] = bi;
    int s = bi & 255, e = bi >> 8;
    if (tid == s) {
#pragma unroll
      for (int e2 = 0; e2 < 8; e2++)
        if (e2 == e) kk[e2] = 0;
      lm = kk[0];
#pragma unroll
      for (int e2 = 1; e2 < 8; e2++) lm = lm > kk[e2] ? lm : kk[e2];
    }
    __syncthreads();
  }
}

// ---------------- column-sum two-phase -------------------------------------
__global__ void k_colsum1(const float* __restrict__ src, float* __restrict__ part,
                          int Lc, int rp) {
  int b = blockIdx.x, ch = blockIdx.y, c = threadIdx.x;
  const float* p = src + ((size_t)b * Lc + (size_t)ch * rp) * 512 + c;
  float s = 0.f;
  for (int r = 0; r < rp; r++) s += p[(size_t)r * 512];
  part[((b << 5) + ch) * 512 + c] = s;
}
__global__ void k_colsum2(const float* __restrict__ part, float* __restrict__ of,
                          u16* __restrict__ oh, int nch, float scale) {
  int b = blockIdx.x, c = threadIdx.x;
  float s = 0.f;
  for (int i = 0; i < nch; i++) s += part[(b * nch + i) * 512 + c];
  s *= scale;
  if (of) of[b * 512 + c] = s;
  if (oh) oh[b * 512 + c] = f2h(s);
}

// ---------------- fill context (fp16) with V-mean --------------------------
__global__ void k_ctx_fillb(u16* __restrict__ ch, const u16* __restrict__ vh,
                            int Lc) {
  int g = blockIdx.x * 256 + threadIdx.x;
  int total = BATCH * Lc * 128;
  if (g >= total) return;
  int c4 = g & 127;
  int row = g >> 7;
  int b = row / Lc;
  ((ushort4*)ch)[g] = ((const ushort4*)vh)[b * 128 + c4];
}

// ---------------- attention: fp16 K/V + fdot2 QK, 5 queries/block ----------
__global__ __launch_bounds__(256) void k_attn_mq(
    const float* __restrict__ Q, const u16* __restrict__ KH,
    const u16* __restrict__ VH, const int* __restrict__ mtop,
    u16* __restrict__ ctxh, int Lc, int u, int nqb) {
  int blk = blockIdx.x;
  int bh = blk & 63;
  int qb = blk >> 6;
  int h = bh & 7, b = bh >> 3;
  int tid = threadIdx.x;
  int lane = tid & 63, wv = tid >> 6;
  __shared__ u32 qpk[5][32];
  __shared__ float s_lds[5][2048];
  __shared__ float wredA[4], wredB[4];
  __shared__ int rows_s[5];
  __shared__ float part[4][5][64];
  for (int qq = tid; qq < 160; qq += 256) {
    int q = qq >> 5, dp = qq & 31;
    int row = mtop[(b * 8 + h) * u + qb * 5 + q];
    if (dp == 0) rows_s[q] = row;
    const float* qp = &Q[((size_t)b * Lc + row) * DMODEL + h * DKH + dp * 2];
    qpk[q][dp] = (u32)f2h(qp[0]) | ((u32)f2h(qp[1]) << 16);
  }
  __syncthreads();
  for (int k = tid; k < Lc; k += 256) {
    const u32* kp = (const u32*)&KH[((size_t)b * Lc + k) * DMODEL + h * DKH];
    float s0 = 0, s1 = 0, s2 = 0, s3 = 0, s4 = 0;
#pragma unroll
    for (int w = 0; w < 32; w++) {
      u32 kw = kp[w];
      s0 = fdot2(kw, qpk[0][w], s0);
      s1 = fdot2(kw, qpk[1][w], s1);
      s2 = fdot2(kw, qpk[2][w], s2);
      s3 = fdot2(kw, qpk[3][w], s3);
      s4 = fdot2(kw, qpk[4][w], s4);
    }
    s_lds[0][k] = s0 * 0.125f;
    s_lds[1][k] = s1 * 0.125f;
    s_lds[2][k] = s2 * 0.125f;
    s_lds[3][k] = s3 * 0.125f;
    s_lds[4][k] = s4 * 0.125f;
  }
  __syncthreads();
  float denomv[5];
#pragma unroll
  for (int q = 0; q < 5; q++) {
    float mx = -INFINITY;
    for (int k = tid; k < Lc; k += 256) mx = fmaxf(mx, s_lds[q][k]);
#pragma unroll
    for (int o = 32; o > 0; o >>= 1) mx = fmaxf(mx, __shfl_xor(mx, o));
    if (lane == 0) wredA[wv] = mx;
    __syncthreads();
    mx = fmaxf(fmaxf(wredA[0], wredA[1]), fmaxf(wredA[2], wredA[3]));
    float ls = 0.f;
    for (int k = tid; k < Lc; k += 256) {
      float w = expf(s_lds[q][k] - mx);
      s_lds[q][k] = w;
      ls += w;
    }
#pragma unroll
    for (int o = 32; o > 0; o >>= 1) ls += __shfl_xor(ls, o);
    if (lane == 0) wredB[wv] = ls;
    __syncthreads();
    denomv[q] = (wredB[0] + wredB[1]) + (wredB[2] + wredB[3]);
  }
  float acc0 = 0, acc1 = 0, acc2 = 0, acc3 = 0, acc4 = 0;
  int chunk = Lc >> 2;
  for (int k = wv * chunk; k < (wv + 1) * chunk; k++) {
    float vvv = h2f(VH[((size_t)b * Lc + k) * DMODEL + h * DKH + lane]);
    acc0 = fmaf(s_lds[0][k], vvv, acc0);
    acc1 = fmaf(s_lds[1][k], vvv, acc1);
    acc2 = fmaf(s_lds[2][k], vvv, acc2);
    acc3 = fmaf(s_lds[3][k], vvv, acc3);
    acc4 = fmaf(s_lds[4][k], vvv, acc4);
  }
  part[wv][0][lane] = acc0;
  part[wv][1][lane] = acc1;
  part[wv][2][lane] = acc2;
  part[wv][3][lane] = acc3;
  part[wv][4][lane] = acc4;
  __syncthreads();
  for (int q = wv; q < 5; q += 4) {
    float tot = ((part[0][q][lane] + part[1][q][lane]) +
                 (part[2][q][lane] + part[3][q][lane])) / denomv[q];
    size_t o = ((size_t)b * Lc + rows_s[q]) * DMODEL + h * DKH + lane;
    ctxh[o] = f2h(tot);
  }
}

// ---------------- y = LayerNorm(x + a [+ a2])*g+b --------------------------
__global__ void k_add_ln(const float* __restrict__ x, const float* __restrict__ a,
                         const float* __restrict__ a2,
                         const float* __restrict__ g, const float* __restrict__ be,
                         float* __restrict__ y, u16* __restrict__ yh) {
  int row = blockIdx.x;
  int tid = threadIdx.x;
  __shared__ float red[256];
  float2 xv = reinterpret_cast<const float2*>(x)[(size_t)row * 256 + tid];
  float2 av = reinterpret_cast<const float2*>(a)[(size_t)row * 256 + tid];
  float vx = xv.x + av.x, vy = xv.y + av.y;
  if (a2) {
    float2 a2v = reinterpret_cast<const float2*>(a2)[(size_t)row * 256 + tid];
    vx += a2v.x;
    vy += a2v.y;
  }
  red[tid] = vx + vy;
  __syncthreads();
  for (int s = 128; s > 0; s >>= 1) {
    if (tid < s) red[tid] += red[tid + s];
    __syncthreads();
  }
  float mean = red[0] * (1.0f / 512.0f);
  __syncthreads();
  float dx = vx - mean, dy = vy - mean;
  red[tid] = dx * dx + dy * dy;
  __syncthreads();
  for (int s = 128; s > 0; s >>= 1) {
    if (tid < s) red[tid] += red[tid + s];
    __syncthreads();
  }
  float rstd = rsqrtf(red[0] * (1.0f / 512.0f) + 1e-5f);
  int c = tid * 2;
  float ox = dx * rstd * g[c] + be[c];
  float oy = dy * rstd * g[c + 1] + be[c + 1];
  if (y) {
    float2 o = {ox, oy};
    reinterpret_cast<float2*>(y)[(size_t)row * 256 + tid] = o;
  }
  if (yh) {
    size_t base = (size_t)row * 512 + c;
    yh[base] = f2h(ox);
    yh[base + 1] = f2h(oy);
  }
}

// ---------------- maxpool of elu(bn(p1+p2)), k=3 s=2 -----------------------
__global__ void k_pool(const float* __restrict__ cv1, const float* __restrict__ cv2,
                       const float* __restrict__ m_, const float* __restrict__ v_,
                       const float* __restrict__ g_, const float* __restrict__ b_,
                       float* __restrict__ out, u16* __restrict__ oh) {
  int g = blockIdx.x * 256 + threadIdx.x;
  int total = BATCH * LL2 * DMODEL;
  if (g >= total) return;
  int c = g & 511;
  int rest = g >> 9;
  int i = rest & (LL2 - 1);
  int b = rest >> 10;
  float bnA = rsqrtf(v_[c] + 1e-5f) * g_[c];
  float bnB = b_[c] - m_[c] * bnA;
  int t0 = 2 * i - 1;
  float mx = -INFINITY;
#pragma unroll
  for (int k = 0; k < 3; k++) {
    int t = t0 + k;
    if (t >= 0 && t < LL1) {
      size_t o = ((size_t)b * LL1 + t) * DMODEL + c;
      float y = (cv1[o] + cv2[o]) * bnA + bnB;
      y = y > 0.f ? y : expm1f(y);
      mx = fmaxf(mx, y);
    }
  }
  out[g] = mx;
  oh[g] = f2h(mx);
}

// ---------------- gx = enc @ wih^T + bih (+ zero lstm tag buffer) ----------
__global__ void k_gx(const float* __restrict__ enc, const float* __restrict__ wih,
                     const float* __restrict__ bih, float* __restrict__ gx,
                     u64* __restrict__ hgl) {
  int g = blockIdx.x * 256 + threadIdx.x;
  if (g < 8192) hgl[g] = 0ull;
  if (g >= BATCH * 2048) return;
  int b = g >> 11, j = g & 2047;
  const float4* wp = reinterpret_cast<const float4*>(&wih[(size_t)j * 512]);
  const float4* ep = reinterpret_cast<const float4*>(&enc[b * 512]);
  float s = bih[j];
  for (int d = 0; d < 128; d++) {
    float4 w = wp[d], e = ep[d];
    s += w.x * e.x + w.y * e.y + w.z * e.z + w.w * e.w;
  }
  gx[g] = s;
}

// ---------------- persistent LSTM v5: tagged-u64 single-RT exchange --------
__global__ __launch_bounds__(256, 1) void k_lstm5(
    const float* __restrict__ gx, const float* __restrict__ whh,
    const float* __restrict__ bhh, const float* __restrict__ ow,
    const float* __restrict__ ob, float* __restrict__ out,
    u64* __restrict__ hglob) {
  const int bl = blockIdx.x, tid = threadIdx.x;
  const int part = tid >> 5, idx = tid & 31;
  const int gtype = idx >> 3, ml = idx & 7;
  const int j = gtype * 512 + bl * 8 + ml;
  __shared__ float h_s[4096];
  __shared__ float red[8][8][32];
  __shared__ float gvs[8][32];
  __shared__ float ow_s[512];
  __shared__ float ored[4];
  float w[64];
  {
    const float* wr = &whh[(size_t)j * 512 + part * 64];
#pragma unroll
    for (int r = 0; r < 64; r += 4) {
      float4 v = *(const float4*)&wr[r];
      w[r] = v.x; w[r + 1] = v.y; w[r + 2] = v.z; w[r + 3] = v.w;
    }
  }
  const float gxrow = gx[part * 2048 + j] + bhh[j];
  float cst = 0.f;
  for (int i = tid; i < 4096; i += 256) h_s[i] = 0.f;
  for (int i = tid; i < 512; i += 256) ow_s[i] = ow[i];
  const float obv = ob[0];
  __syncthreads();
  for (int t = 0; t < TPRED; t++) {
    float p[8];
#pragma unroll
    for (int b = 0; b < 8; b++) p[b] = 0.f;
#pragma unroll
    for (int r = 0; r < 64; r += 4) {
      float w0 = w[r], w1 = w[r + 1], w2 = w[r + 2], w3 = w[r + 3];
#pragma unroll
      for (int b = 0; b < 8; b++) {
        float4 hv = *(const float4*)&h_s[b * 512 + part * 64 + r];
        p[b] = fmaf(w3, hv.w, fmaf(w2, hv.z, fmaf(w1, hv.y, fmaf(w0, hv.x, p[b]))));
      }
    }
#pragma unroll
    for (int b = 0; b < 8; b++) red[b][part][idx] = p[b];
    __syncthreads();
    float gv = gxrow;
#pragma unroll
    for (int pp = 0; pp < 8; pp++) gv += red[part][pp][idx];
    gvs[part][idx] = gv;
    __syncthreads();
    u64* hgb = hglob + ((t + 1) & 1) * 4096;
    const u32 want = (u32)(t + 1);
    if (tid < 64) {
      int b = tid >> 3, m = tid & 7;
      float gi = gvs[b][m], gf = gvs[b][8 + m];
      float gg = gvs[b][16 + m], go = gvs[b][24 + m];
      float c = sigm(gf) * cst + sigm(gi) * tanhf(gg);
      cst = c;
      float hn = sigm(go) * tanhf(c);
      u64 word = ((u64)want << 32) | (u64)__builtin_bit_cast(u32, hn);
      __hip_atomic_store(&hgb[b * 512 + bl * 8 + m], word, __ATOMIC_RELAXED,
                         __HIP_MEMORY_SCOPE_AGENT);
    }
    {
      u64 v[16];
#pragma unroll
      for (int q = 0; q < 16; q++)
        v[q] = __hip_atomic_load(&hgb[q * 256 + tid], __ATOMIC_RELAXED,
                                 __HIP_MEMORY_SCOPE_AGENT);
      bool ok;
      do {
        ok = true;
#pragma unroll
        for (int q = 0; q < 16; q++) {
          if ((u32)(v[q] >> 32) != want) {
            ok = false;
            v[q] = __hip_atomic_load(&hgb[q * 256 + tid], __ATOMIC_RELAXED,
                                     __HIP_MEMORY_SCOPE_AGENT);
          }
        }
      } while (!ok);
#pragma unroll
      for (int q = 0; q < 16; q++)
        h_s[q * 256 + tid] = __builtin_bit_cast(float, (u32)(v[q] & 0xFFFFFFFFull));
    }
    __syncthreads();
    if (bl < 8) {
      float s = h_s[bl * 512 + tid] * ow_s[tid] +
                h_s[bl * 512 + 256 + tid] * ow_s[256 + tid];
#pragma unroll
      for (int o = 32; o > 0; o >>= 1) s += __shfl_xor(s, o);
      if ((tid & 63) == 0) ored[tid >> 6] = s;
      __syncthreads();
      if (tid == 0)
        out[bl * TPRED + t] = (ored[0] + ored[1]) + (ored[2] + ored[3]) + obv;
    }
  }
}

// ---------------------------------------------------------------------------
extern "C" void kernel_launch(void* const* d_in, const int* in_sizes, int n_in,
                              void* d_out, int out_size, void* d_ws, size_t ws_size,
                              hipStream_t stream) {
  const float* x = (const float*)d_in[0];
  const int* idx1 = (const int*)d_in[1];
  const int* idx2 = (const int*)d_in[2];
  const float* emb_w = (const float*)d_in[3];
  const float* emb_b = (const float*)d_in[4];
  const float* wq = (const float*)d_in[5];
  const float* bq = (const float*)d_in[6];
  const float* wk = (const float*)d_in[7];
  const float* bk = (const float*)d_in[8];
  const float* wv = (const float*)d_in[9];
  const float* bv = (const float*)d_in[10];
  const float* wo = (const float*)d_in[11];
  const float* bo = (const float*)d_in[12];
  const float* w1 = (const float*)d_in[13];
  const float* b1 = (const float*)d_in[14];
  const float* w2 = (const float*)d_in[15];
  const float* b2 = (const float*)d_in[16];
  const float* ln1g = (const float*)d_in[17];
  const float* ln1b = (const float*)d_in[18];
  const float* ln2g = (const float*)d_in[19];
  const float* ln2b = (const float*)d_in[20];
  const float* conv_w = (const float*)d_in[21];
  const float* conv_b = (const float*)d_in[22];
  const float* bn_g = (const float*)d_in[23];
  const float* bn_b = (const float*)d_in[24];
  const float* bn_m = (const float*)d_in[25];
  const float* bn_v = (const float*)d_in[26];
  const float* lstm_wih = (const float*)d_in[27];
  const float* lstm_whh = (const float*)d_in[28];
  const float* lstm_bih = (const float*)d_in[29];
  const float* lstm_bhh = (const float*)d_in[30];
  const float* out_w = (const float*)d_in[31];
  const float* out_b = (const float*)d_in[32];
  float* outp = (float*)d_out;

  char* ws = (char*)d_ws;
  const size_t MB = 1 << 20;
  float* S0 = (float*)(ws);
  float* S1 = (float*)(ws + 32 * MB);
  float* S2 = (float*)(ws + 64 * MB);
  float* S3 = (float*)(ws + 96 * MB);
  u16* P0 = (u16*)(ws + 128 * MB);
  u16* P1 = (u16*)(ws + 144 * MB);
  u16* P2 = (u16*)(ws + 160 * MB);
  u16* P3 = (u16*)(ws + 176 * MB);
  float* PP = (float*)(ws + 160 * MB);     // 32MB fp32 alias of P2+P3
  u16* WATT = (u16*)(ws + 192 * MB);
  u16* W1T = (u16*)(ws + 200 * MB);
  u16* W2T = (u16*)(ws + 208 * MB);
  u16* CWT = (u16*)(ws + 216 * MB);
  char* SMB = ws + 220 * MB;
  float* Mbuf = (float*)(SMB);
  float* csp = (float*)(SMB + 512 * 1024);
  u16* vmh = (u16*)(SMB + 1040 * 1024);
  int* mtop = (int*)(SMB + 1056 * 1024);
  float* gxb = (float*)(SMB + 1088 * 1024);
  float* encb = (float*)(SMB + 1152 * 1024);
  u64* hglob = (u64*)(SMB + 1168 * 1024);

  auto wat = [&](int l, int m, int hl) {
    return WATT + ((size_t)(l * 8 + hl * 4 + m)) * 262144;
  };

  {
    dim3 g(4096, 13);
    k_splitall<<<g, 256, 0, stream>>>(wq, wk, wv, wo, w1, w2, conv_w,
                                      WATT, W1T, W2T, CWT);
  }

  // split-K x2 GEMM for N=512: p1 -> C, p2 -> C1 (consumer sums)
  auto mgsk = [&](const u16* Ah, const u16* Bh, const u16* Bl,
                  const float* bias, float* Cb, float* Cp2, int M, int K) {
    dim3 g(2, M / 128, 2);
    k_mgemm<0, 0, 0, 0><<<g, 512, 0, stream>>>(
        Ah, Bh, Bl, bias, nullptr, nullptr, Cb, Cp2, nullptr,
        nullptr, nullptr, nullptr, M, 512, K, 0,
        nullptr, nullptr, nullptr, nullptr);
  };
  auto mg3 = [&](const u16* Ah, const u16* Bh, const u16* Bl,
                 const float* b0_, const float* b1_, const float* b2_,
                 float* C0_, float* C1_, float* C2_, u16* KH, u16* VH, int M) {
    dim3 g(6, M / 128);
    k_mgemm<0, 0, 0, 1><<<g, 512, 0, stream>>>(
        Ah, Bh, Bl, b0_, b1_, b2_, C0_, C1_, C2_,
        nullptr, KH, VH, M, 1536, 512, 0, nullptr, nullptr, nullptr, nullptr);
  };

  // ---------------- embed ----------------
  k_embed<<<(BATCH * LL1) / 8, 256, 0, stream>>>(x, emb_w, emb_b, S0, P0);

  // ---------------- encoder layer 1 (L=2048, u=40) ----------------
  {
    const int Lc = LL1, u = 40, M = BATCH * LL1;
    mg3(P0, wat(0, 0, 0), wat(0, 0, 1), bq, bk, bv, S1, S2, S3, P1, P3, M);
    k_qk_m<<<M, 320, 0, stream>>>(S1, S2, idx1, Mbuf, Lc, u);
    k_topk<<<64, 256, 0, stream>>>(Mbuf, mtop, Lc, u);
    k_colsum1<<<dim3(BATCH, 32), 512, 0, stream>>>(S3, csp, Lc, Lc / 32);
    k_colsum2<<<BATCH, 512, 0, stream>>>(csp, nullptr, vmh, 32, 1.f / Lc);
    k_ctx_fillb<<<(BATCH * Lc * 128) / 256, 256, 0, stream>>>(P2, vmh, Lc);
    k_attn_mq<<<64 * 8, 256, 0, stream>>>(S1, P1, P3, mtop, P2, Lc, u, 8);
    mgsk(P2, wat(0, 3, 0), wat(0, 3, 1), bo, S1, S3, M, 512);
    k_add_ln<<<M, 256, 0, stream>>>(S0, S1, S3, ln1g, ln1b, S2, P0);
    u16* hid16 = (u16*)S0;   // spans S0+S1 (64MB)
    {
      dim3 g1(8, 128);
      k_mgemm<1, 0, 1, 0><<<g1, 512, 0, stream>>>(
          P0, W1T, W1T + 1048576, b1, nullptr, nullptr,
          nullptr, nullptr, nullptr, hid16, nullptr, nullptr,
          16384, 2048, 512, 0, nullptr, nullptr, nullptr, nullptr);
    }
    mgsk(hid16, W2T, W2T + 1048576, b2, S3, PP, M, 2048);
    k_add_ln<<<M, 256, 0, stream>>>(S2, S3, PP, ln2g, ln2b, nullptr, P0);
  }

  // ---------------- conv distill (split-K, BN+ELU in pool) ----------------
  {
    dim3 g(2, 128, 2);
    k_mgemm<0, 1, 0, 0><<<g, 512, 0, stream>>>(
        P0, CWT, CWT + 786432, conv_b, nullptr, nullptr,
        S0, S1, nullptr, nullptr, nullptr, nullptr, 16384, 512, 1536,
        LL1, nullptr, nullptr, nullptr, nullptr);
    k_pool<<<(BATCH * LL2 * 512) / 256, 256, 0, stream>>>(
        S0, S1, bn_m, bn_v, bn_g, bn_b, S2, P0);
  }

  // ---------------- encoder layer 2 (L=1024, u=35) ----------------
  {
    const int Lc = LL2, u = 35, M = BATCH * LL2;
    float* Qb = S1;
    float* Kb = S1 + 4194304;
    float* Vb = S3;
    mg3(P0, wat(1, 0, 0), wat(1, 0, 1), bq + 512, bk + 512, bv + 512,
        Qb, Kb, Vb, P1, P3, M);
    k_qk_m<<<M, 320, 0, stream>>>(Qb, Kb, idx2, Mbuf, Lc, u);
    k_topk<<<64, 256, 0, stream>>>(Mbuf, mtop, Lc, u);
    k_colsum1<<<dim3(BATCH, 32), 512, 0, stream>>>(Vb, csp, Lc, Lc / 32);
    k_colsum2<<<BATCH, 512, 0, stream>>>(csp, nullptr, vmh, 32, 1.f / Lc);
    k_ctx_fillb<<<(BATCH * Lc * 128) / 256, 256, 0, stream>>>(P2, vmh, Lc);
    k_attn_mq<<<64 * 7, 256, 0, stream>>>(Qb, P1, P3, mtop, P2, Lc, u, 7);
    mgsk(P2, wat(1, 3, 0), wat(1, 3, 1), bo + 512, S3, S3 + 4194304, M, 512);
    k_add_ln<<<M, 256, 0, stream>>>(S2, S3, S3 + 4194304,
                                    ln1g + 512, ln1b + 512, S0, P0);
    u16* hid16 = (u16*)S1;   // 32MB
    {
      dim3 g1(8, 64);
      k_mgemm<1, 0, 1, 0><<<g1, 512, 0, stream>>>(
          P0, W1T + (size_t)2 * 1048576, W1T + (size_t)3 * 1048576,
          b1 + 2048, nullptr, nullptr, nullptr, nullptr, nullptr,
          hid16, nullptr, nullptr, 8192, 2048, 512, 0,
          nullptr, nullptr, nullptr, nullptr);
    }
    mgsk(hid16, W2T + (size_t)2 * 1048576, W2T + (size_t)3 * 1048576,
         b2 + 512, S2, S2 + 4194304, M, 2048);
    k_add_ln<<<M, 256, 0, stream>>>(S0, S2, S2 + 4194304,
                                    ln2g + 512, ln2b + 512, S3, nullptr);
  }

  // ---------------- mean -> LSTM -> output ----------------
  k_colsum1<<<dim3(BATCH, 32), 512, 0, stream>>>(S3, csp, LL2, LL2 / 32);
  k_colsum2<<<BATCH, 512, 0, stream>>>(csp, encb, nullptr, 32, 1.f / LL2);
  k_gx<<<(BATCH * 2048) / 256, 256, 0, stream>>>(encb, lstm_wih, lstm_bih, gxb, hglob);
  k_lstm5<<<64, 256, 0, stream>>>(gxb, lstm_whh, lstm_bhh, out_w, out_b, outp, hglob);
}

// Round 14
// 1856.916 us; speedup vs baseline: 1.3256x; 1.0155x over previous
//
#include <hip/hip_runtime.h>
#include <hip/hip_bf16.h>
#include <math.h>

static constexpr int BATCH = 8;
static constexpr int LL1 = 2048;
static constexpr int LL2 = 1024;
static constexpr int DMODEL = 512;
static constexpr int NHEADS = 8;
static constexpr int DKH = 64;
static constexpr int TPRED = 100;

typedef unsigned short u16;
typedef unsigned int u32;
typedef unsigned long long u64;
typedef __attribute__((ext_vector_type(8))) _Float16 half8;
typedef __attribute__((ext_vector_type(2))) _Float16 half2_t;
typedef __attribute__((ext_vector_type(4))) float f32x4;

__device__ __forceinline__ float sigm(float x) { return 1.0f / (1.0f + expf(-x)); }

__device__ __forceinline__ u16 f2h(float f) {
  _Float16 h = (_Float16)f;
  return __builtin_bit_cast(u16, h);
}
__device__ __forceinline__ float h2f(u16 h) {
  return (float)__builtin_bit_cast(_Float16, h);
}
__device__ __forceinline__ float fdot2(u32 a, u32 b, float c) {
  return __builtin_amdgcn_fdot2(__builtin_bit_cast(half2_t, a),
                                __builtin_bit_cast(half2_t, b), c, false);
}

#define GLD16(gsrc, ldst) __builtin_amdgcn_global_load_lds( \
    (const __attribute__((address_space(1))) u32*)(gsrc),   \
    (__attribute__((address_space(3))) u32*)(ldst), 16, 0, 0)

// ---------------- embedding + posenc, writes fp32 + fp16 -------------------
__global__ void k_embed(const float* __restrict__ x, const float* __restrict__ ew,
                        const float* __restrict__ eb, float* __restrict__ out,
                        u16* __restrict__ oh) {
  int r0 = blockIdx.x * 8;
  int tid = threadIdx.x;
  __shared__ float xr[8][64];
  for (int i = tid; i < 512; i += 256)
    xr[i >> 6][i & 63] = x[(size_t)r0 * 64 + i];
  __syncthreads();
  const float fac = -9.210340371976184f / 512.0f;
  int l0 = r0 & (LL1 - 1);
  for (int c = tid; c < DMODEL; c += 256) {
    float acc[8];
#pragma unroll
    for (int r = 0; r < 8; r++) acc[r] = eb[c];
    for (int i = 0; i < 64; i++) {
      float w = ew[i * DMODEL + c];
#pragma unroll
      for (int r = 0; r < 8; r++) acc[r] = fmaf(xr[r][i], w, acc[r]);
    }
    float divv = expf((float)(2 * (c >> 1)) * fac);
#pragma unroll
    for (int r = 0; r < 8; r++) {
      float ang = (float)(l0 + r) * divv;
      float v = acc[r] + ((c & 1) ? cosf(ang) : sinf(ang));
      size_t o = (size_t)(r0 + r) * DMODEL + c;
      out[o] = v;
      oh[o] = f2h(v);
    }
  }
}

// ---------------- MFMA GEMM, 512 thr, 128x256 tile -------------------------
// C = A@(Wh + Wl/1024) + bias. Split-K via gridDim.z==2. MULTI: fused QKV;
// V fp32 write skipped when C2==nullptr (fp16 copy only).
template <int EPI, int CONV, int OSINGLE, int MULTI>
__global__ __launch_bounds__(512, 2) void k_mgemm(
    const u16* __restrict__ Ah,
    const u16* __restrict__ Bh, const u16* __restrict__ Bl,
    const float* __restrict__ bias, const float* __restrict__ bias1,
    const float* __restrict__ bias2,
    float* __restrict__ C, float* __restrict__ C1, float* __restrict__ C2,
    u16* __restrict__ Ch, u16* __restrict__ Kh16, u16* __restrict__ Vh16,
    int M, int N, int K, int Lc,
    const float* __restrict__ p_m, const float* __restrict__ p_v,
    const float* __restrict__ p_g, const float* __restrict__ p_b) {
  __shared__ __align__(16) u16 As[2][4096], Bs_h[2][8192], Bs_l[2][8192];
  const int tid = threadIdx.x;
  const int m0 = blockIdx.y * 128, n0 = blockIdx.x * 256;
  const int wid = tid >> 6, lane = tid & 63;
  const int wm = (wid & 1) * 64, wn = (wid >> 1) * 64;
  const int lr = lane >> 4, lc = lane & 15;
  const int kz = (gridDim.z == 2) ? (int)blockIdx.z : 0;
  const int kb = (gridDim.z == 2) ? kz * (K >> 1) : 0;
  const int ke = (gridDim.z == 2) ? kb + (K >> 1) : K;
  f32x4 acc[4][4], acc2[4][4];
  f32x4 zz = {0.f, 0.f, 0.f, 0.f};
#pragma unroll
  for (int i = 0; i < 4; i++)
#pragma unroll
    for (int j = 0; j < 4; j++) { acc[i][j] = zz; acc2[i][j] = zz; }

  auto stage = [&](int sb, int k0) {
    {
      int c = tid;
      int mi = c >> 2, kc = (c & 3) * 8;
      size_t asrc;
      if (CONV) {
        int m = m0 + mi;
        int b = m >> 11, t = m & (LL1 - 1);
        int kblk = k0 >> 9;
        int srow = (b << 11) + ((t + kblk - 1 + LL1) & (LL1 - 1));
        asrc = (size_t)srow * 512 + (k0 - (kblk << 9)) + kc;
      } else {
        asrc = (size_t)(m0 + mi) * K + k0 + kc;
      }
      GLD16(Ah + asrc, &As[sb][(u32)(c * 8)]);
    }
#pragma unroll
    for (int pass = 0; pass < 2; pass++) {
      int c = tid + pass * 512;
      int mi = c >> 2, kc = (c & 3) * 8;
      size_t bsrc = (size_t)(n0 + mi) * K + k0 + kc;
      u32 ldo = (u32)(c * 8);
      GLD16(Bh + bsrc, &Bs_h[sb][ldo]);
      GLD16(Bl + bsrc, &Bs_l[sb][ldo]);
    }
  };

  stage(0, kb);
  __syncthreads();
  int sb = 0;
  for (int k0 = kb; k0 < ke; k0 += 32) {
    if (k0 + 32 < ke) stage(sb ^ 1, k0 + 32);
    const u16* Ap = As[sb];
    const u16* Bhp = Bs_h[sb];
    const u16* Blp = Bs_l[sb];
    half8 av[4], bh[4], bl[4];
#pragma unroll
    for (int i = 0; i < 4; i++) {
      int ar = (wm + i * 16 + lc) * 32 + lr * 8;
      int br = (wn + i * 16 + lc) * 32 + lr * 8;
      av[i] = *(const half8*)&Ap[ar];
      bh[i] = *(const half8*)&Bhp[br];
      bl[i] = *(const half8*)&Blp[br];
    }
#pragma unroll
    for (int i = 0; i < 4; i++)
#pragma unroll
      for (int j = 0; j < 4; j++) {
        acc[i][j] = __builtin_amdgcn_mfma_f32_16x16x32_f16(av[i], bh[j], acc[i][j], 0, 0, 0);
        acc2[i][j] = __builtin_amdgcn_mfma_f32_16x16x32_f16(av[i], bl[j], acc2[i][j], 0, 0, 0);
      }
    __syncthreads();
    sb ^= 1;
  }
#pragma unroll
  for (int j = 0; j < 4; j++) {
    int col = n0 + wn + j * 16 + lc;
    const float* bp = bias;
    float* Cp = C;
    int cw = col, Nw = N, sel = 0;
    if (MULTI) {
      sel = col >> 9;
      bp = sel == 0 ? bias : (sel == 1 ? bias1 : bias2);
      Cp = sel == 0 ? C : (sel == 1 ? C1 : C2);
      cw = col & 511;
      Nw = 512;
    } else if (kz == 1) {
      Cp = C1;
    }
    float bs = (kz == 0) ? bp[cw] : 0.f;
    float bnA = 0.f, bnB = 0.f;
    if (EPI == 2) {
      bnA = rsqrtf(p_v[cw] + 1e-5f) * p_g[cw];
      bnB = p_b[cw] - p_m[cw] * bnA;
    }
#pragma unroll
    for (int i = 0; i < 4; i++) {
#pragma unroll
      for (int q = 0; q < 4; q++) {
        int row = m0 + wm + i * 16 + lr * 4 + q;
        float t = fmaf(acc2[i][j][q], 0.0009765625f, acc[i][j][q]) + bs;
        if (EPI == 1) t = 0.5f * t * (1.0f + erff(t * 0.7071067811865475f));
        if (EPI == 2) { t = t * bnA + bnB; t = t > 0.f ? t : expm1f(t); }
        size_t o = (size_t)row * Nw + cw;
        if (OSINGLE) {
          Ch[o] = f2h(t);
        } else {
          if (Cp) Cp[o] = t;
          if (MULTI) {
            if (sel == 1 && Kh16) Kh16[o] = f2h(t);
            if (sel == 2 && Vh16) Vh16[o] = f2h(t);
          }
        }
      }
    }
  }
}

// ---------------- fused weight split/transpose (fp16 hi + lo*1024) ---------
__global__ void k_splitall(const float* __restrict__ wq, const float* __restrict__ wk,
                           const float* __restrict__ wv, const float* __restrict__ wo,
                           const float* __restrict__ w1, const float* __restrict__ w2,
                           const float* __restrict__ cw,
                           u16* __restrict__ WATT, u16* __restrict__ W1T,
                           u16* __restrict__ W2T, u16* __restrict__ CWT) {
  int job = blockIdx.y;
  int g = blockIdx.x * 256 + threadIdx.x;
  float v;
  u16 *dh, *dl;
  if (job < 8) {
    if (g >= 262144) return;
    int l = job >> 2, mi = job & 3;
    const float* src = (mi == 0 ? wq : mi == 1 ? wk : mi == 2 ? wv : wo) + (size_t)l * 262144;
    int n = g >> 9, k = g & 511;
    v = src[(size_t)k * 512 + n];
    dh = WATT + (size_t)(l * 8 + mi) * 262144;
    dl = dh + 4 * 262144;
  } else if (job == 8 || job == 10) {
    if (g >= 1048576) return;
    int l = (job == 10);
    int n = g >> 9, k = g & 511;
    v = w1[(size_t)l * 1048576 + (size_t)k * 2048 + n];
    dh = W1T + (size_t)(l * 2) * 1048576;
    dl = dh + 1048576;
  } else if (job == 9 || job == 11) {
    if (g >= 1048576) return;
    int l = (job == 11);
    int n = g >> 11, k = g & 2047;
    v = w2[(size_t)l * 1048576 + (size_t)k * 512 + n];
    dh = W2T + (size_t)(l * 2) * 1048576;
    dl = dh + 1048576;
  } else {
    if (g >= 786432) return;
    int c = g / 1536, k = g - c * 1536;
    int kblk = k >> 9, ci = k & 511;
    v = cw[c * 1536 + ci * 3 + kblk];
    dh = CWT;
    dl = CWT + 786432;
  }
  float wh = (float)(_Float16)v;
  dh[g] = f2h(v);
  dl[g] = f2h((v - wh) * 1024.0f);
}

// ---------------- sampled qk -> M (fp32), XCD-affine block map -------------
// blk&7 = batch so (assuming round-robin XCD dispatch) each batch's K panel
// (4MB fp32) stays resident in one XCD's L2 across its 2048 gathering blocks.
__global__ void k_qk_m(const float* __restrict__ Q, const float* __restrict__ Km,
                       const int* __restrict__ idx, float* __restrict__ Mout,
                       int Lc, int u) {
  int blk = blockIdx.x;
  int b = blk & 7, l = blk >> 3;
  int row = b * Lc + l;
  int tid = threadIdx.x;
  int nt = blockDim.x;
  __shared__ __align__(16) float qlds[DMODEL];
  __shared__ int ilds[40];
  __shared__ float qk[320];
  for (int i = tid; i < DMODEL; i += nt) qlds[i] = Q[(size_t)row * DMODEL + i];
  for (int i = tid; i < u; i += nt) ilds[i] = idx[l * u + i];
  __syncthreads();
  int tot = NHEADS * u;
  if (tid < tot) {
    int j = tid >> 3, h = tid & 7;
    int key = ilds[j];
    const float4* kp = reinterpret_cast<const float4*>(&Km[((size_t)b * Lc + key) * DMODEL + h * DKH]);
    const float4* qp = reinterpret_cast<const float4*>(&qlds[h * DKH]);
    float s = 0.f;
#pragma unroll
    for (int d = 0; d < 16; d++) {
      float4 kv = kp[d], qv = qp[d];
      s += qv.x * kv.x + qv.y * kv.y + qv.z * kv.z + qv.w * kv.w;
    }
    qk[tid] = s;
  }
  __syncthreads();
  if (tid < NHEADS) {
    int h = tid;
    float mx = -INFINITY, sm = 0.f;
    for (int j = 0; j < u; j++) {
      float v = qk[(j << 3) + h];
      mx = fmaxf(mx, v);
      sm += v;
    }
    Mout[((size_t)b * NHEADS + h) * Lc + l] = mx - sm / (float)Lc;
  }
}

// ---------------- top-u: register-resident tournament ----------------------
__global__ void k_topk(const float* __restrict__ Mv, int* __restrict__ mtop,
                       int Lc, int u) {
  int bh = blockIdx.x;
  int tid = threadIdx.x;
  int lane = tid & 63, wv = tid >> 6;
  __shared__ u64 wred[4];
  const int nk = Lc >> 8;
  u64 kk[8];
#pragma unroll
  for (int e = 0; e < 8; e++) {
    u64 key = 0;
    if (e < nk) {
      int i = e * 256 + tid;
      u32 ub = __builtin_bit_cast(u32, Mv[(size_t)bh * Lc + i]);
      ub = (ub & 0x80000000u) ? ~ub : (ub | 0x80000000u);
      key = ((u64)ub << 32) | (u64)(0xFFFFFFFFu - (u32)i);
    }
    kk[e] = key;
  }
  u64 lm = kk[0];
#pragma unroll
  for (int e = 1; e < 8; e++) lm = lm > kk[e] ? lm : kk[e];
  for (int it = 0; it < u; it++) {
    u64 best = lm;
#pragma unroll
    for (int o = 32; o > 0; o >>= 1) {
      u64 other = __shfl_xor(best, o);
      best = best > other ? best : other;
    }
    if (lane == 0) wred[wv] = best;
    __syncthreads();
    u64 b01 = wred[0] > wred[1] ? wred[0] : wred[1];
    u64 b23 = wred[2] > wred[3] ? wred[2] : wred[3];
    u64 b0 = b01 > b23 ? b01 : b23;
    int bi = (int)(0xFFFFFFFFu - (u32)(b0 & 0xFFFFFFFFull));
    if (tid == 0) mtop[bh * u + it] = bi;
    int s = bi & 255, e = bi >> 8;
    if (tid == s) {
#pragma unroll
      for (int e2 = 0; e2 < 8; e2++)
        if (e2 == e) kk[e2] = 0;
      lm = kk[0];
#pragma unroll
      for (int e2 = 1; e2 < 8; e2++) lm = lm > kk[e2] ? lm : kk[e2];
    }
    __syncthreads();
  }
}

// ---------------- column-sum: fp32 source ----------------------------------
__global__ void k_colsum1(const float* __restrict__ src, float* __restrict__ part,
                          int Lc, int rp) {
  int b = blockIdx.x, ch = blockIdx.y, c = threadIdx.x;
  const float* p = src + ((size_t)b * Lc + (size_t)ch * rp) * 512 + c;
  float s = 0.f;
  for (int r = 0; r < rp; r++) s += p[(size_t)r * 512];
  part[((b << 5) + ch) * 512 + c] = s;
}
// ---------------- column-sum: fp16 source (V mean) -------------------------
__global__ void k_colsum1h(const u16* __restrict__ src, float* __restrict__ part,
                           int Lc, int rp) {
  int b = blockIdx.x, ch = blockIdx.y, c = threadIdx.x;
  const u16* p = src + ((size_t)b * Lc + (size_t)ch * rp) * 512 + c;
  float s = 0.f;
  for (int r = 0; r < rp; r++) s += h2f(p[(size_t)r * 512]);
  part[((b << 5) + ch) * 512 + c] = s;
}
__global__ void k_colsum2(const float* __restrict__ part, float* __restrict__ of,
                          u16* __restrict__ oh, int nch, float scale) {
  int b = blockIdx.x, c = threadIdx.x;
  float s = 0.f;
  for (int i = 0; i < nch; i++) s += part[(b * nch + i) * 512 + c];
  s *= scale;
  if (of) of[b * 512 + c] = s;
  if (oh) oh[b * 512 + c] = f2h(s);
}

// ---------------- fill context (fp16) with V-mean --------------------------
__global__ void k_ctx_fillb(u16* __restrict__ ch, const u16* __restrict__ vh,
                            int Lc) {
  int g = blockIdx.x * 256 + threadIdx.x;
  int total = BATCH * Lc * 128;
  if (g >= total) return;
  int c4 = g & 127;
  int row = g >> 7;
  int b = row / Lc;
  ((ushort4*)ch)[g] = ((const ushort4*)vh)[b * 128 + c4];
}

// ---------------- attention: fp16 K/V + fdot2 QK, 5 queries/block ----------
__global__ __launch_bounds__(256) void k_attn_mq(
    const float* __restrict__ Q, const u16* __restrict__ KH,
    const u16* __restrict__ VH, const int* __restrict__ mtop,
    u16* __restrict__ ctxh, int Lc, int u, int nqb) {
  int blk = blockIdx.x;
  int bh = blk & 63;
  int qb = blk >> 6;
  int h = bh & 7, b = bh >> 3;
  int tid = threadIdx.x;
  int lane = tid & 63, wv = tid >> 6;
  __shared__ u32 qpk[5][32];
  __shared__ float s_lds[5][2048];
  __shared__ float wredA[4], wredB[4];
  __shared__ int rows_s[5];
  __shared__ float part[4][5][64];
  for (int qq = tid; qq < 160; qq += 256) {
    int q = qq >> 5, dp = qq & 31;
    int row = mtop[(b * 8 + h) * u + qb * 5 + q];
    if (dp == 0) rows_s[q] = row;
    const float* qp = &Q[((size_t)b * Lc + row) * DMODEL + h * DKH + dp * 2];
    qpk[q][dp] = (u32)f2h(qp[0]) | ((u32)f2h(qp[1]) << 16);
  }
  __syncthreads();
  for (int k = tid; k < Lc; k += 256) {
    const u32* kp = (const u32*)&KH[((size_t)b * Lc + k) * DMODEL + h * DKH];
    float s0 = 0, s1 = 0, s2 = 0, s3 = 0, s4 = 0;
#pragma unroll
    for (int w = 0; w < 32; w++) {
      u32 kw = kp[w];
      s0 = fdot2(kw, qpk[0][w], s0);
      s1 = fdot2(kw, qpk[1][w], s1);
      s2 = fdot2(kw, qpk[2][w], s2);
      s3 = fdot2(kw, qpk[3][w], s3);
      s4 = fdot2(kw, qpk[4][w], s4);
    }
    s_lds[0][k] = s0 * 0.125f;
    s_lds[1][k] = s1 * 0.125f;
    s_lds[2][k] = s2 * 0.125f;
    s_lds[3][k] = s3 * 0.125f;
    s_lds[4][k] = s4 * 0.125f;
  }
  __syncthreads();
  float denomv[5];
#pragma unroll
  for (int q = 0; q < 5; q++) {
    float mx = -INFINITY;
    for (int k = tid; k < Lc; k += 256) mx = fmaxf(mx, s_lds[q][k]);
#pragma unroll
    for (int o = 32; o > 0; o >>= 1) mx = fmaxf(mx, __shfl_xor(mx, o));
    if (lane == 0) wredA[wv] = mx;
    __syncthreads();
    mx = fmaxf(fmaxf(wredA[0], wredA[1]), fmaxf(wredA[2], wredA[3]));
    float ls = 0.f;
    for (int k = tid; k < Lc; k += 256) {
      float w = expf(s_lds[q][k] - mx);
      s_lds[q][k] = w;
      ls += w;
    }
#pragma unroll
    for (int o = 32; o > 0; o >>= 1) ls += __shfl_xor(ls, o);
    if (lane == 0) wredB[wv] = ls;
    __syncthreads();
    denomv[q] = (wredB[0] + wredB[1]) + (wredB[2] + wredB[3]);
  }
  float acc0 = 0, acc1 = 0, acc2 = 0, acc3 = 0, acc4 = 0;
  int chunk = Lc >> 2;
  for (int k = wv * chunk; k < (wv + 1) * chunk; k++) {
    float vvv = h2f(VH[((size_t)b * Lc + k) * DMODEL + h * DKH + lane]);
    acc0 = fmaf(s_lds[0][k], vvv, acc0);
    acc1 = fmaf(s_lds[1][k], vvv, acc1);
    acc2 = fmaf(s_lds[2][k], vvv, acc2);
    acc3 = fmaf(s_lds[3][k], vvv, acc3);
    acc4 = fmaf(s_lds[4][k], vvv, acc4);
  }
  part[wv][0][lane] = acc0;
  part[wv][1][lane] = acc1;
  part[wv][2][lane] = acc2;
  part[wv][3][lane] = acc3;
  part[wv][4][lane] = acc4;
  __syncthreads();
  for (int q = wv; q < 5; q += 4) {
    float tot = ((part[0][q][lane] + part[1][q][lane]) +
                 (part[2][q][lane] + part[3][q][lane])) / denomv[q];
    size_t o = ((size_t)b * Lc + rows_s[q]) * DMODEL + h * DKH + lane;
    ctxh[o] = f2h(tot);
  }
}

// ---------------- LayerNorm: 1 wave per row, shuffle-only ------------------
__global__ void k_add_ln(const float* __restrict__ x, const float* __restrict__ a,
                         const float* __restrict__ a2,
                         const float* __restrict__ g, const float* __restrict__ be,
                         float* __restrict__ y, u16* __restrict__ yh) {
  int row = blockIdx.x * 4 + (threadIdx.x >> 6);
  int lane = threadIdx.x & 63;
  size_t base = (size_t)row * 512 + lane * 8;
  float4 x0 = *(const float4*)&x[base];
  float4 x1 = *(const float4*)&x[base + 4];
  float4 a0 = *(const float4*)&a[base];
  float4 a1 = *(const float4*)&a[base + 4];
  float v[8];
  v[0] = x0.x + a0.x; v[1] = x0.y + a0.y; v[2] = x0.z + a0.z; v[3] = x0.w + a0.w;
  v[4] = x1.x + a1.x; v[5] = x1.y + a1.y; v[6] = x1.z + a1.z; v[7] = x1.w + a1.w;
  if (a2) {
    float4 b0 = *(const float4*)&a2[base];
    float4 b1 = *(const float4*)&a2[base + 4];
    v[0] += b0.x; v[1] += b0.y; v[2] += b0.z; v[3] += b0.w;
    v[4] += b1.x; v[5] += b1.y; v[6] += b1.z; v[7] += b1.w;
  }
  float s = ((v[0] + v[1]) + (v[2] + v[3])) + ((v[4] + v[5]) + (v[6] + v[7]));
#pragma unroll
  for (int o = 32; o > 0; o >>= 1) s += __shfl_xor(s, o);
  float mean = s * (1.0f / 512.0f);
  float vs = 0.f;
#pragma unroll
  for (int i = 0; i < 8; i++) {
    v[i] -= mean;
    vs = fmaf(v[i], v[i], vs);
  }
#pragma unroll
  for (int o = 32; o > 0; o >>= 1) vs += __shfl_xor(vs, o);
  float rstd = rsqrtf(vs * (1.0f / 512.0f) + 1e-5f);
  int c = lane * 8;
  float4 g0 = *(const float4*)&g[c];
  float4 g1 = *(const float4*)&g[c + 4];
  float4 e0 = *(const float4*)&be[c];
  float4 e1 = *(const float4*)&be[c + 4];
  float o_[8];
  o_[0] = v[0] * rstd * g0.x + e0.x; o_[1] = v[1] * rstd * g0.y + e0.y;
  o_[2] = v[2] * rstd * g0.z + e0.z; o_[3] = v[3] * rstd * g0.w + e0.w;
  o_[4] = v[4] * rstd * g1.x + e1.x; o_[5] = v[5] * rstd * g1.y + e1.y;
  o_[6] = v[6] * rstd * g1.z + e1.z; o_[7] = v[7] * rstd * g1.w + e1.w;
  if (y) {
    float4 w0 = {o_[0], o_[1], o_[2], o_[3]};
    float4 w1 = {o_[4], o_[5], o_[6], o_[7]};
    *(float4*)&y[base] = w0;
    *(float4*)&y[base + 4] = w1;
  }
  if (yh) {
    ushort4 h0 = {f2h(o_[0]), f2h(o_[1]), f2h(o_[2]), f2h(o_[3])};
    ushort4 h1 = {f2h(o_[4]), f2h(o_[5]), f2h(o_[6]), f2h(o_[7])};
    *(ushort4*)&yh[base] = h0;
    *(ushort4*)&yh[base + 4] = h1;
  }
}

// ---------------- maxpool of elu(bn(p1+p2)), k=3 s=2 -----------------------
__global__ void k_pool(const float* __restrict__ cv1, const float* __restrict__ cv2,
                       const float* __restrict__ m_, const float* __restrict__ v_,
                       const float* __restrict__ g_, const float* __restrict__ b_,
                       float* __restrict__ out, u16* __restrict__ oh) {
  int g = blockIdx.x * 256 + threadIdx.x;
  int total = BATCH * LL2 * DMODEL;
  if (g >= total) return;
  int c = g & 511;
  int rest = g >> 9;
  int i = rest & (LL2 - 1);
  int b = rest >> 10;
  float bnA = rsqrtf(v_[c] + 1e-5f) * g_[c];
  float bnB = b_[c] - m_[c] * bnA;
  int t0 = 2 * i - 1;
  float mx = -INFINITY;
#pragma unroll
  for (int k = 0; k < 3; k++) {
    int t = t0 + k;
    if (t >= 0 && t < LL1) {
      size_t o = ((size_t)b * LL1 + t) * DMODEL + c;
      float y = (cv1[o] + cv2[o]) * bnA + bnB;
      y = y > 0.f ? y : expm1f(y);
      mx = fmaxf(mx, y);
    }
  }
  out[g] = mx;
  oh[g] = f2h(mx);
}

// ---------------- gx = enc @ wih^T + bih (+ zero lstm tag buffer) ----------
__global__ void k_gx(const float* __restrict__ enc, const float* __restrict__ wih,
                     const float* __restrict__ bih, float* __restrict__ gx,
                     u64* __restrict__ hgl) {
  int g = blockIdx.x * 256 + threadIdx.x;
  if (g < 8192) hgl[g] = 0ull;
  if (g >= BATCH * 2048) return;
  int b = g >> 11, j = g & 2047;
  const float4* wp = reinterpret_cast<const float4*>(&wih[(size_t)j * 512]);
  const float4* ep = reinterpret_cast<const float4*>(&enc[b * 512]);
  float s = bih[j];
  for (int d = 0; d < 128; d++) {
    float4 w = wp[d], e = ep[d];
    s += w.x * e.x + w.y * e.y + w.z * e.z + w.w * e.w;
  }
  gx[g] = s;
}

// ---------------- persistent LSTM v5: tagged-u64 single-RT exchange --------
__global__ __launch_bounds__(256, 1) void k_lstm5(
    const float* __restrict__ gx, const float* __restrict__ whh,
    const float* __restrict__ bhh, const float* __restrict__ ow,
    const float* __restrict__ ob, float* __restrict__ out,
    u64* __restrict__ hglob) {
  const int bl = blockIdx.x, tid = threadIdx.x;
  const int part = tid >> 5, idx = tid & 31;
  const int gtype = idx >> 3, ml = idx & 7;
  const int j = gtype * 512 + bl * 8 + ml;
  __shared__ float h_s[4096];
  __shared__ float red[8][8][32];
  __shared__ float gvs[8][32];
  __shared__ float ow_s[512];
  __shared__ float ored[4];
  float w[64];
  {
    const float* wr = &whh[(size_t)j * 512 + part * 64];
#pragma unroll
    for (int r = 0; r < 64; r += 4) {
      float4 v = *(const float4*)&wr[r];
      w[r] = v.x; w[r + 1] = v.y; w[r + 2] = v.z; w[r + 3] = v.w;
    }
  }
  const float gxrow = gx[part * 2048 + j] + bhh[j];
  float cst = 0.f;
  for (int i = tid; i < 4096; i += 256) h_s[i] = 0.f;
  for (int i = tid; i < 512; i += 256) ow_s[i] = ow[i];
  const float obv = ob[0];
  __syncthreads();
  for (int t = 0; t < TPRED; t++) {
    float p[8];
#pragma unroll
    for (int b = 0; b < 8; b++) p[b] = 0.f;
#pragma unroll
    for (int r = 0; r < 64; r += 4) {
      float w0 = w[r], w1 = w[r + 1], w2 = w[r + 2], w3 = w[r + 3];
#pragma unroll
      for (int b = 0; b < 8; b++) {
        float4 hv = *(const float4*)&h_s[b * 512 + part * 64 + r];
        p[b] = fmaf(w3, hv.w, fmaf(w2, hv.z, fmaf(w1, hv.y, fmaf(w0, hv.x, p[b]))));
      }
    }
#pragma unroll
    for (int b = 0; b < 8; b++) red[b][part][idx] = p[b];
    __syncthreads();
    float gv = gxrow;
#pragma unroll
    for (int pp = 0; pp < 8; pp++) gv += red[part][pp][idx];
    gvs[part][idx] = gv;
    __syncthreads();
    u64* hgb = hglob + ((t + 1) & 1) * 4096;
    const u32 want = (u32)(t + 1);
    if (tid < 64) {
      int b = tid >> 3, m = tid & 7;
      float gi = gvs[b][m], gf = gvs[b][8 + m];
      float gg = gvs[b][16 + m], go = gvs[b][24 + m];
      float c = sigm(gf) * cst + sigm(gi) * tanhf(gg);
      cst = c;
      float hn = sigm(go) * tanhf(c);
      u64 word = ((u64)want << 32) | (u64)__builtin_bit_cast(u32, hn);
      __hip_atomic_store(&hgb[b * 512 + bl * 8 + m], word, __ATOMIC_RELAXED,
                         __HIP_MEMORY_SCOPE_AGENT);
    }
    {
      u64 v[16];
#pragma unroll
      for (int q = 0; q < 16; q++)
        v[q] = __hip_atomic_load(&hgb[q * 256 + tid], __ATOMIC_RELAXED,
                                 __HIP_MEMORY_SCOPE_AGENT);
      bool ok;
      do {
        ok = true;
#pragma unroll
        for (int q = 0; q < 16; q++) {
          if ((u32)(v[q] >> 32) != want) {
            ok = false;
            v[q] = __hip_atomic_load(&hgb[q * 256 + tid], __ATOMIC_RELAXED,
                                     __HIP_MEMORY_SCOPE_AGENT);
          }
        }
      } while (!ok);
#pragma unroll
      for (int q = 0; q < 16; q++)
        h_s[q * 256 + tid] = __builtin_bit_cast(float, (u32)(v[q] & 0xFFFFFFFFull));
    }
    __syncthreads();
    if (bl < 8) {
      float s = h_s[bl * 512 + tid] * ow_s[tid] +
                h_s[bl * 512 + 256 + tid] * ow_s[256 + tid];
#pragma unroll
      for (int o = 32; o > 0; o >>= 1) s += __shfl_xor(s, o);
      if ((tid & 63) == 0) ored[tid >> 6] = s;
      __syncthreads();
      if (tid == 0)
        out[bl * TPRED + t] = (ored[0] + ored[1]) + (ored[2] + ored[3]) + obv;
    }
  }
}

// ---------------------------------------------------------------------------
extern "C" void kernel_launch(void* const* d_in, const int* in_sizes, int n_in,
                              void* d_out, int out_size, void* d_ws, size_t ws_size,
                              hipStream_t stream) {
  const float* x = (const float*)d_in[0];
  const int* idx1 = (const int*)d_in[1];
  const int* idx2 = (const int*)d_in[2];
  const float* emb_w = (const float*)d_in[3];
  const float* emb_b = (const float*)d_in[4];
  const float* wq = (const float*)d_in[5];
  const float* bq = (const float*)d_in[6];
  const float* wk = (const float*)d_in[7];
  const float* bk = (const float*)d_in[8];
  const float* wv = (const float*)d_in[9];
  const float* bv = (const float*)d_in[10];
  const float* wo = (const float*)d_in[11];
  const float* bo = (const float*)d_in[12];
  const float* w1 = (const float*)d_in[13];
  const float* b1 = (const float*)d_in[14];
  const float* w2 = (const float*)d_in[15];
  const float* b2 = (const float*)d_in[16];
  const float* ln1g = (const float*)d_in[17];
  const float* ln1b = (const float*)d_in[18];
  const float* ln2g = (const float*)d_in[19];
  const float* ln2b = (const float*)d_in[20];
  const float* conv_w = (const float*)d_in[21];
  const float* conv_b = (const float*)d_in[22];
  const float* bn_g = (const float*)d_in[23];
  const float* bn_b = (const float*)d_in[24];
  const float* bn_m = (const float*)d_in[25];
  const float* bn_v = (const float*)d_in[26];
  const float* lstm_wih = (const float*)d_in[27];
  const float* lstm_whh = (const float*)d_in[28];
  const float* lstm_bih = (const float*)d_in[29];
  const float* lstm_bhh = (const float*)d_in[30];
  const float* out_w = (const float*)d_in[31];
  const float* out_b = (const float*)d_in[32];
  float* outp = (float*)d_out;

  char* ws = (char*)d_ws;
  const size_t MB = 1 << 20;
  float* S0 = (float*)(ws);
  float* S1 = (float*)(ws + 32 * MB);
  float* S2 = (float*)(ws + 64 * MB);
  float* S3 = (float*)(ws + 96 * MB);
  u16* P0 = (u16*)(ws + 128 * MB);
  u16* P1 = (u16*)(ws + 144 * MB);
  u16* P2 = (u16*)(ws + 160 * MB);
  u16* P3 = (u16*)(ws + 176 * MB);
  float* PP = (float*)(ws + 160 * MB);     // 32MB fp32 alias of P2+P3
  u16* WATT = (u16*)(ws + 192 * MB);
  u16* W1T = (u16*)(ws + 200 * MB);
  u16* W2T = (u16*)(ws + 208 * MB);
  u16* CWT = (u16*)(ws + 216 * MB);
  char* SMB = ws + 220 * MB;
  float* Mbuf = (float*)(SMB);
  float* csp = (float*)(SMB + 512 * 1024);
  u16* vmh = (u16*)(SMB + 1040 * 1024);
  int* mtop = (int*)(SMB + 1056 * 1024);
  float* gxb = (float*)(SMB + 1088 * 1024);
  float* encb = (float*)(SMB + 1152 * 1024);
  u64* hglob = (u64*)(SMB + 1168 * 1024);

  auto wat = [&](int l, int m, int hl) {
    return WATT + ((size_t)(l * 8 + hl * 4 + m)) * 262144;
  };

  {
    dim3 g(4096, 13);
    k_splitall<<<g, 256, 0, stream>>>(wq, wk, wv, wo, w1, w2, conv_w,
                                      WATT, W1T, W2T, CWT);
  }

  auto mgsk = [&](const u16* Ah, const u16* Bh, const u16* Bl,
                  const float* bias, float* Cb, float* Cp2, int M, int K) {
    dim3 g(2, M / 128, 2);
    k_mgemm<0, 0, 0, 0><<<g, 512, 0, stream>>>(
        Ah, Bh, Bl, bias, nullptr, nullptr, Cb, Cp2, nullptr,
        nullptr, nullptr, nullptr, M, 512, K, 0,
        nullptr, nullptr, nullptr, nullptr);
  };
  auto mg3 = [&](const u16* Ah, const u16* Bh, const u16* Bl,
                 const float* b0_, const float* b1_, const float* b2_,
                 float* C0_, float* C1_, u16* KH, u16* VH, int M) {
    dim3 g(6, M / 128);
    k_mgemm<0, 0, 0, 1><<<g, 512, 0, stream>>>(
        Ah, Bh, Bl, b0_, b1_, b2_, C0_, C1_, nullptr,
        nullptr, KH, VH, M, 1536, 512, 0, nullptr, nullptr, nullptr, nullptr);
  };

  // ---------------- embed ----------------
  k_embed<<<(BATCH * LL1) / 8, 256, 0, stream>>>(x, emb_w, emb_b, S0, P0);

  // ---------------- encoder layer 1 (L=2048, u=40) ----------------
  {
    const int Lc = LL1, u = 40, M = BATCH * LL1;
    mg3(P0, wat(0, 0, 0), wat(0, 0, 1), bq, bk, bv, S1, S2, P1, P3, M);
    k_qk_m<<<M, 320, 0, stream>>>(S1, S2, idx1, Mbuf, Lc, u);
    k_topk<<<64, 256, 0, stream>>>(Mbuf, mtop, Lc, u);
    k_colsum1h<<<dim3(BATCH, 32), 512, 0, stream>>>(P3, csp, Lc, Lc / 32);
    k_colsum2<<<BATCH, 512, 0, stream>>>(csp, nullptr, vmh, 32, 1.f / Lc);
    k_ctx_fillb<<<(BATCH * Lc * 128) / 256, 256, 0, stream>>>(P2, vmh, Lc);
    k_attn_mq<<<64 * 8, 256, 0, stream>>>(S1, P1, P3, mtop, P2, Lc, u, 8);
    mgsk(P2, wat(0, 3, 0), wat(0, 3, 1), bo, S1, S3, M, 512);
    k_add_ln<<<M / 4, 256, 0, stream>>>(S0, S1, S3, ln1g, ln1b, S2, P0);
    u16* hid16 = (u16*)S0;   // spans S0+S1 (64MB)
    {
      dim3 g1(8, 128);
      k_mgemm<1, 0, 1, 0><<<g1, 512, 0, stream>>>(
          P0, W1T, W1T + 1048576, b1, nullptr, nullptr,
          nullptr, nullptr, nullptr, hid16, nullptr, nullptr,
          16384, 2048, 512, 0, nullptr, nullptr, nullptr, nullptr);
    }
    mgsk(hid16, W2T, W2T + 1048576, b2, S3, PP, M, 2048);
    k_add_ln<<<M / 4, 256, 0, stream>>>(S2, S3, PP, ln2g, ln2b, nullptr, P0);
  }

  // ---------------- conv distill (split-K, BN+ELU in pool) ----------------
  {
    dim3 g(2, 128, 2);
    k_mgemm<0, 1, 0, 0><<<g, 512, 0, stream>>>(
        P0, CWT, CWT + 786432, conv_b, nullptr, nullptr,
        S0, S1, nullptr, nullptr, nullptr, nullptr, 16384, 512, 1536,
        LL1, nullptr, nullptr, nullptr, nullptr);
    k_pool<<<(BATCH * LL2 * 512) / 256, 256, 0, stream>>>(
        S0, S1, bn_m, bn_v, bn_g, bn_b, S2, P0);
  }

  // ---------------- encoder layer 2 (L=1024, u=35) ----------------
  {
    const int Lc = LL2, u = 35, M = BATCH * LL2;
    float* Qb = S1;
    float* Kb = S1 + 4194304;
    mg3(P0, wat(1, 0, 0), wat(1, 0, 1), bq + 512, bk + 512, bv + 512,
        Qb, Kb, P1, P3, M);
    k_qk_m<<<M, 320, 0, stream>>>(Qb, Kb, idx2, Mbuf, Lc, u);
    k_topk<<<64, 256, 0, stream>>>(Mbuf, mtop, Lc, u);
    k_colsum1h<<<dim3(BATCH, 32), 512, 0, stream>>>(P3, csp, Lc, Lc / 32);
    k_colsum2<<<BATCH, 512, 0, stream>>>(csp, nullptr, vmh, 32, 1.f / Lc);
    k_ctx_fillb<<<(BATCH * Lc * 128) / 256, 256, 0, stream>>>(P2, vmh, Lc);
    k_attn_mq<<<64 * 7, 256, 0, stream>>>(Qb, P1, P3, mtop, P2, Lc, u, 7);
    mgsk(P2, wat(1, 3, 0), wat(1, 3, 1), bo + 512, S3, S3 + 4194304, M, 512);
    k_add_ln<<<M / 4, 256, 0, stream>>>(S2, S3, S3 + 4194304,
                                        ln1g + 512, ln1b + 512, S0, P0);
    u16* hid16 = (u16*)S1;   // 32MB
    {
      dim3 g1(8, 64);
      k_mgemm<1, 0, 1, 0><<<g1, 512, 0, stream>>>(
          P0, W1T + (size_t)2 * 1048576, W1T + (size_t)3 * 1048576,
          b1 + 2048, nullptr, nullptr, nullptr, nullptr, nullptr,
          hid16, nullptr, nullptr, 8192, 2048, 512, 0,
          nullptr, nullptr, nullptr, nullptr);
    }
    mgsk(hid16, W2T + (size_t)2 * 1048576, W2T + (size_t)3 * 1048576,
         b2 + 512, S2, S2 + 4194304, M, 2048);
    k_add_ln<<<M / 4, 256, 0, stream>>>(S0, S2, S2 + 4194304,
                                        ln2g + 512, ln2b + 512, S3, nullptr);
  }

  // ---------------- mean -> LSTM -> output ----------------
  k_colsum1<<<dim3(BATCH, 32), 512, 0, stream>>>(S3, csp, LL2, LL2 / 32);
  k_colsum2<<<BATCH, 512, 0, stream>>>(csp, encb, nullptr, 32, 1.f / LL2);
  k_gx<<<(BATCH * 2048) / 256, 256, 0, stream>>>(encb, lstm_wih, lstm_bih, gxb, hglob);
  k_lstm5<<<64, 256, 0, stream>>>(gxb, lstm_whh, lstm_bhh, out_w, out_b, outp, hglob);
}